// Round 5
// baseline (2444.113 us; speedup 1.0000x reference)
//
#include <hip/hip_runtime.h>
#include <hip/hip_bf16.h>

// Problem constants
#define NB    16
#define NC    256
#define NHW   4096      // 64*64
#define NPIX  65536     // NB*NHW
#define NE    1024
#define BETA  0.25f
#define DECAY 0.99f
#define EPS_  1e-5f
#define GAP_FLAG 1.25e-4f   // 4x coarse ulp(256..512): quantized-tie danger zone

// d_out layout (floats):
//   [0, 16777216)             out (NCHW z_q straight-through, 16*256*64*64)
//   [16777216]                loss
//   [16777217, +65536)        idx (as float)
//   [16842753, +1024)         new_cluster_size
//   [16843777, +262144)       new_embedding_avg
//   [17105921, +262144)       new_weight
#define OFF_LOSS 16777216
#define OFF_IDXF 16777217
#define OFF_NCS  16842753
#define OFF_NEA  16843777
#define OFF_NW   17105921

// square with FMA-contraction barrier: guarantees round(mul) then round(add),
// matching numpy's separate multiply + pairwise-add semantics.
__device__ __forceinline__ float sq_nofma(float x) {
    float s = x * x;
    asm volatile("" : "+v"(s));
    return s;
}

// numpy pairwise_sum of 128 squares (block<=128 path: 8 accumulators,
// combine ((r0+r1)+(r2+r3))+((r4+r5)+(r6+r7))), bit-exact vs np.float32.
__device__ __forceinline__ float np_pair128_sq(const float* __restrict__ a) {
    float r[8];
    #pragma unroll
    for (int m = 0; m < 8; ++m) r[m] = sq_nofma(a[m]);
    for (int i = 8; i < 128; i += 8) {
        #pragma unroll
        for (int m = 0; m < 8; ++m) r[m] += sq_nofma(a[i + m]);
    }
    return ((r[0] + r[1]) + (r[2] + r[3])) + ((r[4] + r[5]) + (r[6] + r[7]));
}

// ---- K0a: nea = 0.99*ea; zero counts accumulator (ncs slot) and loss slot --
__global__ __launch_bounds__(256) void init_kernel(const float* __restrict__ ea,
                                                   float* __restrict__ nea,
                                                   float* __restrict__ ncs,
                                                   float* __restrict__ loss) {
    int gid = blockIdx.x * 256 + threadIdx.x;
    nea[gid] = DECAY * ea[gid];            // grid covers exactly 262144
    if (gid < NE) ncs[gid] = 0.0f;
    if (gid == 0) loss[0] = 0.0f;
}

// ---- K0b: wsum[j] = np.float32 pairwise sum of w[j][:]^2 -------------------
__global__ __launch_bounds__(64) void wsum_kernel(const float* __restrict__ w,
                                                  float* __restrict__ wsum) {
    int j = blockIdx.x * 64 + threadIdx.x;          // grid 16 -> 1024 codes
    const float* wr = w + (size_t)j * NC;
    float left  = np_pair128_sq(wr);
    float right = np_pair128_sq(wr + 128);
    wsum[j] = left + right;                          // n=256 split: left+right
}

// ---- K1: fp32 continuous argmin + top-2 gap; near-quantum pixels flagged ---
__global__ __launch_bounds__(256) void argmin_kernel(const float* __restrict__ z,
                                                     const float* __restrict__ w,
                                                     const float* __restrict__ enorm,
                                                     float* __restrict__ idxf,
                                                     unsigned long long* __restrict__ flags) {
    __shared__ __align__(16) float smem[64 * 68 + 128 * 68];  // zt | wt (52.2 KB)
    float* zt = smem;             // [64 px][68]
    float* wt = smem + 64 * 68;   // [128 code][68]

    const int t  = threadIdx.x;
    const int pr = t & 7;
    const int cr = t >> 3;        // 0..31
    const int P0 = blockIdx.x * 64;
    const int b  = P0 >> 12;
    const int hw0 = P0 & (NHW - 1);
    const float* zb = z + (size_t)b * (NC * NHW) + hw0;   // + c*NHW + p

    float bestv[8], secv[8];
    int   besti[8];
    #pragma unroll
    for (int i = 0; i < 8; ++i) { bestv[i] = 3.4e38f; secv[i] = 3.4e38f; besti[i] = 0; }

    for (int cc = 0; cc < 8; ++cc) {
        float acc[8][4];
        #pragma unroll
        for (int i = 0; i < 8; ++i)
            #pragma unroll
            for (int j = 0; j < 4; ++j) acc[i][j] = 0.0f;

        for (int kc = 0; kc < 4; ++kc) {
            {   // stage z tile: 64 px x 64 k
                int p = t & 63;
                int k0 = (t >> 6) * 16;
                #pragma unroll
                for (int i = 0; i < 16; ++i) {
                    int k = k0 + i;
                    zt[p * 68 + k] = zb[(size_t)(kc * 64 + k) * NHW + p];
                }
            }
            {   // stage w tile: 128 codes x 64 k (float4)
                #pragma unroll
                for (int i = 0; i < 8; ++i) {
                    int f  = t + 256 * i;       // 0..2047
                    int jj = f >> 4;            // 0..127
                    int k4 = f & 15;
                    float4 v = *(const float4*)&w[(size_t)(cc * 128 + jj) * NC + kc * 64 + k4 * 4];
                    *(float4*)&wt[jj * 68 + k4 * 4] = v;
                }
            }
            __syncthreads();
            #pragma unroll 2
            for (int k = 0; k < 64; k += 4) {
                float4 za[8], wb[4];
                #pragma unroll
                for (int i = 0; i < 8; ++i)
                    za[i] = *(float4*)&zt[(pr + 8 * i) * 68 + k];
                #pragma unroll
                for (int j = 0; j < 4; ++j)
                    wb[j] = *(float4*)&wt[(cr + 32 * j) * 68 + k];
                #pragma unroll
                for (int i = 0; i < 8; ++i)
                    #pragma unroll
                    for (int j = 0; j < 4; ++j)
                        acc[i][j] += za[i].x * wb[j].x + za[i].y * wb[j].y +
                                     za[i].z * wb[j].z + za[i].w * wb[j].w;
            }
            __syncthreads();
        }
        #pragma unroll
        for (int j = 0; j < 4; ++j) {
            int code = cc * 128 + cr + 32 * j;
            float en = enorm[code];
            #pragma unroll
            for (int i = 0; i < 8; ++i) {
                float s = en - 2.0f * acc[i][j];
                if (s < bestv[i]) { secv[i] = bestv[i]; bestv[i] = s; besti[i] = code; }
                else if (s < secv[i]) secv[i] = s;   // codes ascending in-thread
            }
        }
    }

    // block-wide per-pixel top-2 reduce (reuse smem)
    float* rv = smem;                      // [64][32] best value
    int*   ri = (int*)(smem + 2048);       // [64][32] best index
    float* rs = smem + 4096;               // [64][32] second value
    #pragma unroll
    for (int i = 0; i < 8; ++i) {
        int p = pr + 8 * i;
        rv[p * 32 + cr] = bestv[i];
        ri[p * 32 + cr] = besti[i];
        rs[p * 32 + cr] = secv[i];
    }
    __syncthreads();
    if (t < 64) {
        int p = t;
        float bv = rv[p * 32], sv = rs[p * 32];
        int   bi = ri[p * 32];
        for (int s2 = 1; s2 < 32; ++s2) {
            float v  = rv[p * 32 + s2];
            float v2 = rs[p * 32 + s2];
            int   ii = ri[p * 32 + s2];
            if (v < bv) { sv = bv; bv = v; bi = ii; }
            else {
                if (v < sv) sv = v;
                if (v == bv && ii < bi) bi = ii;
            }
            if (v2 < sv) sv = v2;
        }
        idxf[P0 + p] = (float)bi;
        unsigned long long mask = __ballot((sv - bv) < GAP_FLAG);
        if (t == 0) flags[blockIdx.x] = mask;
    }
}

// ---- K1b: np-fp32-mimic re-argmin for flagged pixels -----------------------
// d_j = fl32( fl32(zsum_np + wsum_np[j]) - 2*fl32(dot64) ), argmin first-index.
__global__ __launch_bounds__(256) void fixup_kernel(const float* __restrict__ z,
                                                    const float* __restrict__ w,
                                                    const float* __restrict__ wsum,
                                                    const unsigned long long* __restrict__ flags,
                                                    float* __restrict__ idxf) {
    unsigned long long m = flags[blockIdx.x];
    if (m == 0ULL) return;
    const int t  = threadIdx.x;
    const int P0 = blockIdx.x * 64;
    const int b  = P0 >> 12;
    const int hw0 = P0 & (NHW - 1);
    __shared__ float zrow[NC];
    __shared__ float zsum_sh;
    __shared__ float rbv[256];
    __shared__ int   rbi[256];
    while (m) {
        int p = __ffsll(m) - 1;
        m &= (m - 1);
        zrow[t] = z[(size_t)b * (NC * NHW) + (size_t)t * NHW + hw0 + p];
        __syncthreads();
        if (t == 0) {
            float left  = np_pair128_sq(zrow);
            float right = np_pair128_sq(zrow + 128);
            zsum_sh = left + right;          // numpy pairwise, bit-exact
        }
        __syncthreads();
        const float zs = zsum_sh;
        float bv = 3.4e38f; int bi = 0;
        #pragma unroll
        for (int jj = 0; jj < 4; ++jj) {
            int j = t + 256 * jj;                  // ascending in-thread
            const float* wr = &w[(size_t)j * NC];
            double dot = 0.0;
            #pragma unroll 4
            for (int k = 0; k < NC; ++k)
                dot += (double)wr[k] * (double)zrow[k];
            float mj = (float)dot;                 // single round to fp32
            float s1 = zs + wsum[j];               // fl32 add (quantized ~256)
            float dj = s1 - 2.0f * mj;             // fl32 sub
            if (dj < bv) { bv = dj; bi = j; }      // strict < => first index
        }
        rbv[t] = bv; rbi[t] = bi;
        __syncthreads();
        if (t == 0) {
            float gbv = rbv[0]; int gbi = rbi[0];
            for (int i = 1; i < 256; ++i) {
                if (rbv[i] < gbv || (rbv[i] == gbv && rbi[i] < gbi)) { gbv = rbv[i]; gbi = rbi[i]; }
            }
            idxf[P0 + p] = (float)gbi;
        }
        __syncthreads();
    }
}

// ---- K2: z_q out, loss SSE (loss slot), counts (ncs slot), dw into nea -----
__global__ __launch_bounds__(256) void scatter_kernel(const float* __restrict__ z,
                                                      const float* __restrict__ w,
                                                      const float* __restrict__ idxf,
                                                      float* __restrict__ outq,
                                                      float* __restrict__ nea,
                                                      float* __restrict__ ncs,
                                                      float* __restrict__ loss) {
    const int t  = threadIdx.x;
    const int P0 = blockIdx.x * 64;
    const int b  = P0 >> 12;
    const int hw0 = P0 & (NHW - 1);
    __shared__ int sidx[64];
    if (t < 64) {
        int id = ((int)idxf[P0 + t]) & (NE - 1);
        sidx[t] = id;
        atomicAdd(&ncs[id], 1.0f);
    }
    __syncthreads();
    const int p  = t & 63;
    const int id = sidx[p];
    const size_t base = (size_t)b * (NC * NHW) + hw0 + p;
    float lsum = 0.0f;
    #pragma unroll 4
    for (int ci = 0; ci < 64; ++ci) {
        int c = (t >> 6) + 4 * ci;          // one c per wave -> coalesced z/out
        size_t a = base + (size_t)c * NHW;
        float zv = z[a];
        float qv = w[(size_t)id * NC + c];  // gather, L2-hot (1 MB table)
        outq[a] = qv;
        float d = qv - zv;
        lsum += d * d;
        atomicAdd(&nea[(size_t)id * NC + c], (1.0f - DECAY) * zv);
    }
    #pragma unroll
    for (int off = 32; off > 0; off >>= 1) lsum += __shfl_down(lsum, off);
    __shared__ float ls[4];
    if ((t & 63) == 0) ls[t >> 6] = lsum;
    __syncthreads();
    if (t == 0) atomicAdd(&loss[0], ls[0] + ls[1] + ls[2] + ls[3]);
}

// ---- K3: finalize ncs (reads counts from its own slot), cssm (ws), loss ----
__global__ __launch_bounds__(1024) void finalize_kernel(const float* __restrict__ cs,
                                                        float* __restrict__ ncs,
                                                        float* __restrict__ cssm,
                                                        float* __restrict__ loss) {
    int t = threadIdx.x;
    float cnt = ncs[t];                      // counts accumulated by scatter
    float v = cs[t] * DECAY + (1.0f - DECAY) * cnt;
    ncs[t] = v;
    __shared__ float red[1024];
    red[t] = v;
    __syncthreads();
    for (int s = 512; s > 0; s >>= 1) {
        if (t < s) red[t] += red[t + s];
        __syncthreads();
    }
    float n = red[0];
    cssm[t] = (v + EPS_) / (n + (float)NE * EPS_) * n;
    if (t == 0) loss[0] = BETA * loss[0] / 16777216.0f;
}

// ---- K4: new_weight = nea / cs_smoothed ------------------------------------
__global__ __launch_bounds__(256) void newweight_kernel(const float* __restrict__ nea,
                                                        const float* __restrict__ cssm,
                                                        float* __restrict__ nw) {
    int lin = blockIdx.x * 256 + threadIdx.x;
    nw[lin] = nea[lin] / cssm[lin >> 8];
}

extern "C" void kernel_launch(void* const* d_in, const int* in_sizes, int n_in,
                              void* d_out, int out_size, void* d_ws, size_t ws_size,
                              hipStream_t stream) {
    const float* z  = (const float*)d_in[0];
    const float* w  = (const float*)d_in[1];
    const float* cs = (const float*)d_in[2];
    const float* ea = (const float*)d_in[3];

    float* out  = (float*)d_out;
    float* loss = out + OFF_LOSS;
    float* idxf = out + OFF_IDXF;
    float* ncs  = out + OFF_NCS;
    float* nea  = out + OFF_NEA;
    float* nw   = out + OFF_NW;

    float* wsf   = (float*)d_ws;
    float* wsum  = wsf;                                        // 1024 floats
    float* cssm  = wsf + NE;                                   // 1024 floats
    unsigned long long* flags = (unsigned long long*)(wsf + 2 * NE);  // 1024 u64

    hipLaunchKernelGGL(init_kernel,      dim3(1024), dim3(256),  0, stream, ea, nea, ncs, loss);
    hipLaunchKernelGGL(wsum_kernel,      dim3(16),   dim3(64),   0, stream, w, wsum);
    hipLaunchKernelGGL(argmin_kernel,    dim3(1024), dim3(256),  0, stream, z, w, wsum, idxf, flags);
    hipLaunchKernelGGL(fixup_kernel,     dim3(1024), dim3(256),  0, stream, z, w, wsum, flags, idxf);
    hipLaunchKernelGGL(scatter_kernel,   dim3(1024), dim3(256),  0, stream, z, w, idxf, out, nea, ncs, loss);
    hipLaunchKernelGGL(finalize_kernel,  dim3(1),    dim3(1024), 0, stream, cs, ncs, cssm, loss);
    hipLaunchKernelGGL(newweight_kernel, dim3(1024), dim3(256),  0, stream, nea, cssm, nw);
}

// Round 6
// 1598.170 us; speedup vs baseline: 1.5293x; 1.5293x over previous
//
#include <hip/hip_runtime.h>
#include <hip/hip_bf16.h>

// Problem constants
#define NB    16
#define NC    256
#define NHW   4096      // 64*64
#define NPIX  65536     // NB*NHW
#define NE    1024
#define BETA  0.25f
#define DECAY 0.99f
#define EPS_  1e-5f
#define GAP_FLAG 1.25e-4f   // 4x coarse ulp(256..512): quantized-tie danger zone

// d_out layout (floats):
#define OFF_LOSS 16777216
#define OFF_IDXF 16777217
#define OFF_NCS  16842753
#define OFF_NEA  16843777
#define OFF_NW   17105921

// square with FMA-contraction barrier (match np mul-then-add rounding)
__device__ __forceinline__ float sq_nofma(float x) {
    float s = x * x;
    asm volatile("" : "+v"(s));
    return s;
}

// numpy pairwise_sum of 128 squares (8 accumulators, np's combine tree)
__device__ __forceinline__ float np_pair128_sq(const float* __restrict__ a) {
    float r[8];
    #pragma unroll
    for (int m = 0; m < 8; ++m) r[m] = sq_nofma(a[m]);
    for (int i = 8; i < 128; i += 8) {
        #pragma unroll
        for (int m = 0; m < 8; ++m) r[m] += sq_nofma(a[i + m]);
    }
    return ((r[0] + r[1]) + (r[2] + r[3])) + ((r[4] + r[5]) + (r[6] + r[7]));
}

// ---- K0a: zero counts accumulator (ncs slot) -------------------------------
__global__ __launch_bounds__(256) void init_kernel(float* __restrict__ ncs) {
    int gid = blockIdx.x * 256 + threadIdx.x;
    if (gid < NE) ncs[gid] = 0.0f;
}

// ---- K0b: wsum[j] = np.float32 pairwise sum of w[j][:]^2 -------------------
__global__ __launch_bounds__(64) void wsum_kernel(const float* __restrict__ w,
                                                  float* __restrict__ wsum) {
    int j = blockIdx.x * 64 + threadIdx.x;          // grid 16 -> 1024 codes
    const float* wr = w + (size_t)j * NC;
    float left  = np_pair128_sq(wr);
    float right = np_pair128_sq(wr + 128);
    wsum[j] = left + right;
}

// ---- K1: fp32 continuous argmin + top-2 gap; near-quantum pixels flagged ---
__global__ __launch_bounds__(256) void argmin_kernel(const float* __restrict__ z,
                                                     const float* __restrict__ w,
                                                     const float* __restrict__ enorm,
                                                     float* __restrict__ idxf,
                                                     unsigned long long* __restrict__ flags) {
    __shared__ __align__(16) float smem[64 * 68 + 128 * 68];  // zt | wt (52.2 KB)
    float* zt = smem;             // [64 px][68], k-index XOR-swizzled
    float* wt = smem + 64 * 68;   // [128 code][68]

    const int t  = threadIdx.x;
    const int pr = t & 7;
    const int cr = t >> 3;
    const int P0 = blockIdx.x * 64;
    const int b  = P0 >> 12;
    const int hw0 = P0 & (NHW - 1);
    const float* zb = z + (size_t)b * (NC * NHW) + hw0;

    float bestv[8], secv[8];
    int   besti[8];
    #pragma unroll
    for (int i = 0; i < 8; ++i) { bestv[i] = 3.4e38f; secv[i] = 3.4e38f; besti[i] = 0; }

    for (int cc = 0; cc < 8; ++cc) {
        float acc[8][4];
        #pragma unroll
        for (int i = 0; i < 8; ++i)
            #pragma unroll
            for (int j = 0; j < 4; ++j) acc[i][j] = 0.0f;

        for (int kc = 0; kc < 4; ++kc) {
            {   // stage z tile: 64 px x 64 k, swizzled k ^= ((p>>3)&3)<<2
                int p = t & 63;
                int k0 = (t >> 6) * 16;
                int f2 = ((p >> 3) & 3) << 2;
                #pragma unroll
                for (int i = 0; i < 16; ++i) {
                    int k = k0 + i;
                    zt[p * 68 + (k ^ f2)] = zb[(size_t)(kc * 64 + k) * NHW + p];
                }
            }
            {   // stage w tile: 128 codes x 64 k (float4)
                #pragma unroll
                for (int i = 0; i < 8; ++i) {
                    int f  = t + 256 * i;       // 0..2047
                    int jj = f >> 4;            // 0..127
                    int k4 = f & 15;
                    float4 v = *(const float4*)&w[(size_t)(cc * 128 + jj) * NC + kc * 64 + k4 * 4];
                    *(float4*)&wt[jj * 68 + k4 * 4] = v;
                }
            }
            __syncthreads();
            #pragma unroll 2
            for (int k = 0; k < 64; k += 4) {
                float4 za[8], wb[4];
                #pragma unroll
                for (int i = 0; i < 8; ++i)
                    za[i] = *(float4*)&zt[(pr + 8 * i) * 68 + (k ^ ((i & 3) << 2))];
                #pragma unroll
                for (int j = 0; j < 4; ++j)
                    wb[j] = *(float4*)&wt[(cr + 32 * j) * 68 + k];
                #pragma unroll
                for (int i = 0; i < 8; ++i)
                    #pragma unroll
                    for (int j = 0; j < 4; ++j)
                        acc[i][j] += za[i].x * wb[j].x + za[i].y * wb[j].y +
                                     za[i].z * wb[j].z + za[i].w * wb[j].w;
            }
            __syncthreads();
        }
        #pragma unroll
        for (int j = 0; j < 4; ++j) {
            int code = cc * 128 + cr + 32 * j;
            float en = enorm[code];
            #pragma unroll
            for (int i = 0; i < 8; ++i) {
                float s = en - 2.0f * acc[i][j];
                if (s < bestv[i]) { secv[i] = bestv[i]; bestv[i] = s; besti[i] = code; }
                else if (s < secv[i]) secv[i] = s;   // codes ascending in-thread
            }
        }
    }

    // block-wide per-pixel top-2 reduce (reuse smem)
    float* rv = smem;                      // [64][32] best value
    int*   ri = (int*)(smem + 2048);       // [64][32] best index
    float* rs = smem + 4096;               // [64][32] second value
    #pragma unroll
    for (int i = 0; i < 8; ++i) {
        int p = pr + 8 * i;
        rv[p * 32 + cr] = bestv[i];
        ri[p * 32 + cr] = besti[i];
        rs[p * 32 + cr] = secv[i];
    }
    __syncthreads();
    if (t < 64) {
        int p = t;
        float bv = rv[p * 32], sv = rs[p * 32];
        int   bi = ri[p * 32];
        for (int s2 = 1; s2 < 32; ++s2) {
            float v  = rv[p * 32 + s2];
            float v2 = rs[p * 32 + s2];
            int   ii = ri[p * 32 + s2];
            if (v < bv) { sv = bv; bv = v; bi = ii; }
            else {
                if (v < sv) sv = v;
                if (v == bv && ii < bi) bi = ii;
            }
            if (v2 < sv) sv = v2;
        }
        idxf[P0 + p] = (float)bi;
        unsigned long long mask = __ballot((sv - bv) < GAP_FLAG);
        if (t == 0) flags[blockIdx.x] = mask;
    }
}

// ---- K1b: np-fp32-mimic re-argmin for flagged pixels -----------------------
__global__ __launch_bounds__(256) void fixup_kernel(const float* __restrict__ z,
                                                    const float* __restrict__ w,
                                                    const float* __restrict__ wsum,
                                                    const unsigned long long* __restrict__ flags,
                                                    float* __restrict__ idxf) {
    unsigned long long m = flags[blockIdx.x];
    if (m == 0ULL) return;
    const int t  = threadIdx.x;
    const int P0 = blockIdx.x * 64;
    const int b  = P0 >> 12;
    const int hw0 = P0 & (NHW - 1);
    __shared__ float zrow[NC];
    __shared__ float zsum_sh;
    __shared__ float rbv[256];
    __shared__ int   rbi[256];
    while (m) {
        int p = __ffsll(m) - 1;
        m &= (m - 1);
        zrow[t] = z[(size_t)b * (NC * NHW) + (size_t)t * NHW + hw0 + p];
        __syncthreads();
        if (t == 0) {
            float left  = np_pair128_sq(zrow);
            float right = np_pair128_sq(zrow + 128);
            zsum_sh = left + right;
        }
        __syncthreads();
        const float zs = zsum_sh;
        float bv = 3.4e38f; int bi = 0;
        #pragma unroll
        for (int jj = 0; jj < 4; ++jj) {
            int j = t + 256 * jj;
            const float* wr = &w[(size_t)j * NC];
            double dot = 0.0;
            #pragma unroll 4
            for (int k = 0; k < NC; ++k)
                dot += (double)wr[k] * (double)zrow[k];
            float mj = (float)dot;
            float s1 = zs + wsum[j];
            float dj = s1 - 2.0f * mj;
            if (dj < bv) { bv = dj; bi = j; }
        }
        rbv[t] = bv; rbi[t] = bi;
        __syncthreads();
        if (t == 0) {
            float gbv = rbv[0]; int gbi = rbi[0];
            for (int i = 1; i < 256; ++i) {
                if (rbv[i] < gbv || (rbv[i] == gbv && rbi[i] < gbi)) { gbv = rbv[i]; gbi = rbi[i]; }
            }
            idxf[P0 + p] = (float)gbi;
        }
        __syncthreads();
    }
}

// ---- K2a: counts histogram -> ncs (16 flush atomics per code) --------------
__global__ __launch_bounds__(1024) void hist_kernel(const float* __restrict__ idxf,
                                                    float* __restrict__ ncs) {
    __shared__ int h[NE];
    int t = threadIdx.x;
    h[t] = 0;
    __syncthreads();
    int gid = blockIdx.x * 1024 + t;          // grid 16
    #pragma unroll
    for (int i = 0; i < 4; ++i) {
        int p = gid + i * 16384;
        atomicAdd(&h[(int)idxf[p]], 1);
    }
    __syncthreads();
    if (h[t]) atomicAdd(&ncs[t], (float)h[t]);
}

// ---- K2b: streaming z_q out + loss partials (no hot atomics) ---------------
__global__ __launch_bounds__(256) void out_kernel(const float* __restrict__ z,
                                                  const float* __restrict__ w,
                                                  const float* __restrict__ idxf,
                                                  float* __restrict__ outq,
                                                  float* __restrict__ lpart) {
    const int t   = threadIdx.x;
    const int gid = blockIdx.x * 256 + t;     // grid 1024 -> 262144 threads
    float lsum = 0.0f;
    // each thread: 64 floats = 4 chunks of 16 consecutive (same b,c row)
    #pragma unroll
    for (int ch = 0; ch < 4; ++ch) {
        size_t e0 = ((size_t)gid + (size_t)ch * 262144) * 16;
        int b   = (int)(e0 >> 20);
        int hw0 = (int)(e0 & (NHW - 1));
        int c   = (int)((e0 >> 12) & 255);
        int pix0 = (b << 12) + hw0;
        #pragma unroll
        for (int q = 0; q < 4; ++q) {
            float4 zv = *(const float4*)&z[e0 + q * 4];
            float4 ov;
            float* po = &ov.x;
            const float* pz = &zv.x;
            #pragma unroll
            for (int k = 0; k < 4; ++k) {
                int id = (int)idxf[pix0 + q * 4 + k];
                float qv = w[(size_t)id * NC + c];
                po[k] = qv;
                float d = qv - pz[k];
                lsum += d * d;
            }
            *(float4*)&outq[e0 + q * 4] = ov;
        }
    }
    #pragma unroll
    for (int off = 32; off > 0; off >>= 1) lsum += __shfl_down(lsum, off);
    __shared__ float ls[4];
    if ((t & 63) == 0) ls[t >> 6] = lsum;
    __syncthreads();
    if (t == 0) lpart[blockIdx.x] = ls[0] + ls[1] + ls[2] + ls[3];
}

// ---- K2c: dw segmented-sum per channel via LDS; direct nea write -----------
__global__ __launch_bounds__(1024) void dwsum_kernel(const float* __restrict__ z,
                                                     const float* __restrict__ idxf,
                                                     const float* __restrict__ ea,
                                                     float* __restrict__ nea) {
    __shared__ float acc[NE];
    const int c = blockIdx.x;                 // grid 256: one channel per block
    const int t = threadIdx.x;
    acc[t] = 0.0f;
    __syncthreads();
    const float* zc = z + (size_t)c * NHW;    // + b*(NC*NHW) + hw
    #pragma unroll 4
    for (int i = 0; i < 64; ++i) {
        int p  = i * 1024 + t;                // pixel id, coalesced
        int b  = p >> 12;
        int hw = p & (NHW - 1);
        float zv = zc[(size_t)b * (NC * NHW) + hw];
        int id = (int)idxf[p];
        atomicAdd(&acc[id], zv);
    }
    __syncthreads();
    size_t o = (size_t)t * NC + c;            // code t, channel c
    nea[o] = DECAY * ea[o] + (1.0f - DECAY) * acc[t];
}

// ---- K3: finalize ncs EMA, n, cssm, loss from partials ---------------------
__global__ __launch_bounds__(1024) void finalize_kernel(const float* __restrict__ cs,
                                                        const float* __restrict__ lpart,
                                                        float* __restrict__ ncs,
                                                        float* __restrict__ cssm,
                                                        float* __restrict__ loss) {
    int t = threadIdx.x;
    float cnt = ncs[t];
    float v = cs[t] * DECAY + (1.0f - DECAY) * cnt;
    ncs[t] = v;
    __shared__ float red[1024];
    red[t] = v;
    __syncthreads();
    for (int s = 512; s > 0; s >>= 1) {
        if (t < s) red[t] += red[t + s];
        __syncthreads();
    }
    float n = red[0];
    __syncthreads();
    cssm[t] = (v + EPS_) / (n + (float)NE * EPS_) * n;
    // loss reduction
    red[t] = lpart[t];
    __syncthreads();
    for (int s = 512; s > 0; s >>= 1) {
        if (t < s) red[t] += red[t + s];
        __syncthreads();
    }
    if (t == 0) loss[0] = BETA * red[0] / 16777216.0f;
}

// ---- K4: new_weight = nea / cs_smoothed ------------------------------------
__global__ __launch_bounds__(256) void newweight_kernel(const float* __restrict__ nea,
                                                        const float* __restrict__ cssm,
                                                        float* __restrict__ nw) {
    int lin = blockIdx.x * 256 + threadIdx.x;
    nw[lin] = nea[lin] / cssm[lin >> 8];
}

extern "C" void kernel_launch(void* const* d_in, const int* in_sizes, int n_in,
                              void* d_out, int out_size, void* d_ws, size_t ws_size,
                              hipStream_t stream) {
    const float* z  = (const float*)d_in[0];
    const float* w  = (const float*)d_in[1];
    const float* cs = (const float*)d_in[2];
    const float* ea = (const float*)d_in[3];

    float* out  = (float*)d_out;
    float* loss = out + OFF_LOSS;
    float* idxf = out + OFF_IDXF;
    float* ncs  = out + OFF_NCS;
    float* nea  = out + OFF_NEA;
    float* nw   = out + OFF_NW;

    float* wsf   = (float*)d_ws;
    float* wsum  = wsf;                                        // 1024 floats
    float* cssm  = wsf + NE;                                   // 1024 floats
    unsigned long long* flags = (unsigned long long*)(wsf + 2 * NE);  // 1024 u64
    float* lpart = wsf + 4 * NE;                               // 1024 floats (20 KB total)

    hipLaunchKernelGGL(init_kernel,      dim3(4),    dim3(256),  0, stream, ncs);
    hipLaunchKernelGGL(wsum_kernel,      dim3(16),   dim3(64),   0, stream, w, wsum);
    hipLaunchKernelGGL(argmin_kernel,    dim3(1024), dim3(256),  0, stream, z, w, wsum, idxf, flags);
    hipLaunchKernelGGL(fixup_kernel,     dim3(1024), dim3(256),  0, stream, z, w, wsum, flags, idxf);
    hipLaunchKernelGGL(hist_kernel,      dim3(16),   dim3(1024), 0, stream, idxf, ncs);
    hipLaunchKernelGGL(out_kernel,       dim3(1024), dim3(256),  0, stream, z, w, idxf, out, lpart);
    hipLaunchKernelGGL(dwsum_kernel,     dim3(256),  dim3(1024), 0, stream, z, idxf, ea, nea);
    hipLaunchKernelGGL(finalize_kernel,  dim3(1),    dim3(1024), 0, stream, cs, lpart, ncs, cssm, loss);
    hipLaunchKernelGGL(newweight_kernel, dim3(1024), dim3(256),  0, stream, nea, cssm, nw);
}

// Round 7
// 1007.493 us; speedup vs baseline: 2.4259x; 1.5863x over previous
//
#include <hip/hip_runtime.h>
#include <hip/hip_bf16.h>

// Problem constants
#define NB    16
#define NC    256
#define NHW   4096      // 64*64
#define NPIX  65536     // NB*NHW
#define NE    1024
#define BETA  0.25f
#define DECAY 0.99f
#define EPS_  1e-5f
#define GAP_FLAG 1.25e-4f   // 4x coarse ulp(256..512): quantized-tie danger zone

// d_out layout (floats):
#define OFF_LOSS 16777216
#define OFF_IDXF 16777217
#define OFF_NCS  16842753
#define OFF_NEA  16843777
#define OFF_NW   17105921

// square with FMA-contraction barrier (match np mul-then-add rounding)
__device__ __forceinline__ float sq_nofma(float x) {
    float s = x * x;
    asm volatile("" : "+v"(s));
    return s;
}

// numpy pairwise_sum of 128 squares (8 accumulators, np's combine tree)
__device__ __forceinline__ float np_pair128_sq(const float* __restrict__ a) {
    float r[8];
    #pragma unroll
    for (int m = 0; m < 8; ++m) r[m] = sq_nofma(a[m]);
    for (int i = 8; i < 128; i += 8) {
        #pragma unroll
        for (int m = 0; m < 8; ++m) r[m] += sq_nofma(a[i + m]);
    }
    return ((r[0] + r[1]) + (r[2] + r[3])) + ((r[4] + r[5]) + (r[6] + r[7]));
}

// ---- K0a: zero counts accumulator (ncs slot) + fixup list counter ----------
__global__ __launch_bounds__(256) void init_kernel(float* __restrict__ ncs,
                                                   int* __restrict__ cnt) {
    int gid = blockIdx.x * 256 + threadIdx.x;
    if (gid < NE) ncs[gid] = 0.0f;
    if (gid == 0) cnt[0] = 0;
}

// ---- K0b: wsum[j] = np.float32 pairwise sum of w[j][:]^2 -------------------
__global__ __launch_bounds__(64) void wsum_kernel(const float* __restrict__ w,
                                                  float* __restrict__ wsum) {
    int j = blockIdx.x * 64 + threadIdx.x;          // grid 16 -> 1024 codes
    const float* wr = w + (size_t)j * NC;
    float left  = np_pair128_sq(wr);
    float right = np_pair128_sq(wr + 128);
    wsum[j] = left + right;
}

// ---- K1: fp32 continuous argmin + top-2 gap; near-quantum pixels flagged ---
__global__ __launch_bounds__(256) void argmin_kernel(const float* __restrict__ z,
                                                     const float* __restrict__ w,
                                                     const float* __restrict__ enorm,
                                                     float* __restrict__ idxf,
                                                     unsigned long long* __restrict__ flags) {
    __shared__ __align__(16) float smem[64 * 68 + 128 * 68];  // zt | wt (52.2 KB)
    float* zt = smem;             // [64 px][68], k-index XOR-swizzled
    float* wt = smem + 64 * 68;   // [128 code][68]

    const int t  = threadIdx.x;
    const int pr = t & 7;
    const int cr = t >> 3;
    const int P0 = blockIdx.x * 64;
    const int b  = P0 >> 12;
    const int hw0 = P0 & (NHW - 1);
    const float* zb = z + (size_t)b * (NC * NHW) + hw0;

    float bestv[8], secv[8];
    int   besti[8];
    #pragma unroll
    for (int i = 0; i < 8; ++i) { bestv[i] = 3.4e38f; secv[i] = 3.4e38f; besti[i] = 0; }

    for (int cc = 0; cc < 8; ++cc) {
        float acc[8][4];
        #pragma unroll
        for (int i = 0; i < 8; ++i)
            #pragma unroll
            for (int j = 0; j < 4; ++j) acc[i][j] = 0.0f;

        for (int kc = 0; kc < 4; ++kc) {
            {   // stage z tile: 64 px x 64 k, swizzled k ^= ((p>>3)&3)<<2
                int p = t & 63;
                int k0 = (t >> 6) * 16;
                int f2 = ((p >> 3) & 3) << 2;
                #pragma unroll
                for (int i = 0; i < 16; ++i) {
                    int k = k0 + i;
                    zt[p * 68 + (k ^ f2)] = zb[(size_t)(kc * 64 + k) * NHW + p];
                }
            }
            {   // stage w tile: 128 codes x 64 k (float4)
                #pragma unroll
                for (int i = 0; i < 8; ++i) {
                    int f  = t + 256 * i;       // 0..2047
                    int jj = f >> 4;            // 0..127
                    int k4 = f & 15;
                    float4 v = *(const float4*)&w[(size_t)(cc * 128 + jj) * NC + kc * 64 + k4 * 4];
                    *(float4*)&wt[jj * 68 + k4 * 4] = v;
                }
            }
            __syncthreads();
            #pragma unroll 2
            for (int k = 0; k < 64; k += 4) {
                float4 za[8], wb[4];
                #pragma unroll
                for (int i = 0; i < 8; ++i)
                    za[i] = *(float4*)&zt[(pr + 8 * i) * 68 + (k ^ ((i & 3) << 2))];
                #pragma unroll
                for (int j = 0; j < 4; ++j)
                    wb[j] = *(float4*)&wt[(cr + 32 * j) * 68 + k];
                #pragma unroll
                for (int i = 0; i < 8; ++i)
                    #pragma unroll
                    for (int j = 0; j < 4; ++j)
                        acc[i][j] += za[i].x * wb[j].x + za[i].y * wb[j].y +
                                     za[i].z * wb[j].z + za[i].w * wb[j].w;
            }
            __syncthreads();
        }
        #pragma unroll
        for (int j = 0; j < 4; ++j) {
            int code = cc * 128 + cr + 32 * j;
            float en = enorm[code];
            #pragma unroll
            for (int i = 0; i < 8; ++i) {
                float s = en - 2.0f * acc[i][j];
                if (s < bestv[i]) { secv[i] = bestv[i]; bestv[i] = s; besti[i] = code; }
                else if (s < secv[i]) secv[i] = s;   // codes ascending in-thread
            }
        }
    }

    // block-wide per-pixel top-2 reduce (reuse smem)
    float* rv = smem;                      // [64][32] best value
    int*   ri = (int*)(smem + 2048);       // [64][32] best index
    float* rs = smem + 4096;               // [64][32] second value
    #pragma unroll
    for (int i = 0; i < 8; ++i) {
        int p = pr + 8 * i;
        rv[p * 32 + cr] = bestv[i];
        ri[p * 32 + cr] = besti[i];
        rs[p * 32 + cr] = secv[i];
    }
    __syncthreads();
    if (t < 64) {
        int p = t;
        float bv = rv[p * 32], sv = rs[p * 32];
        int   bi = ri[p * 32];
        for (int s2 = 1; s2 < 32; ++s2) {
            float v  = rv[p * 32 + s2];
            float v2 = rs[p * 32 + s2];
            int   ii = ri[p * 32 + s2];
            if (v < bv) { sv = bv; bv = v; bi = ii; }
            else {
                if (v < sv) sv = v;
                if (v == bv && ii < bi) bi = ii;
            }
            if (v2 < sv) sv = v2;
        }
        idxf[P0 + p] = (float)bi;
        unsigned long long mask = __ballot((sv - bv) < GAP_FLAG);
        if (t == 0) flags[blockIdx.x] = mask;
    }
}

// ---- K1b-a: compact flagged pixels into a list -----------------------------
__global__ __launch_bounds__(256) void gather_kernel(const unsigned long long* __restrict__ flags,
                                                     unsigned short* __restrict__ list,
                                                     int* __restrict__ cnt) {
    int p = blockIdx.x * 256 + threadIdx.x;     // grid 256 -> 65536 pixels
    unsigned long long m = flags[p >> 6];
    if ((m >> (p & 63)) & 1ULL) {
        int pos = atomicAdd(cnt, 1);
        list[pos] = (unsigned short)p;
    }
}

// ---- K1b-b: np-fp32-mimic re-argmin, one block per flagged pixel -----------
// d_j = fl32( fl32(zsum_np + wsum_np[j]) - 2*fl32(dot64) ), argmin first-index.
__global__ __launch_bounds__(256) void fixup2_kernel(const float* __restrict__ z,
                                                     const float* __restrict__ w,
                                                     const float* __restrict__ wsum,
                                                     const unsigned short* __restrict__ list,
                                                     const int* __restrict__ cnt,
                                                     float* __restrict__ idxf) {
    const int count = cnt[0];
    const int t = threadIdx.x;
    __shared__ float  zrowf[NC];
    __shared__ double zrowd[NC];
    __shared__ float  zs_sh;
    __shared__ float  rbv[256];
    __shared__ int    rbi[256];
    for (int i = blockIdx.x; i < count; i += gridDim.x) {
        int p  = list[i];
        int b  = p >> 12;
        int hw = p & (NHW - 1);
        float zv = z[(size_t)b * (NC * NHW) + (size_t)t * NHW + hw];
        zrowf[t] = zv;
        zrowd[t] = (double)zv;
        __syncthreads();
        if (t == 0) {
            float left  = np_pair128_sq(zrowf);
            float right = np_pair128_sq(zrowf + 128);
            zs_sh = left + right;                // numpy pairwise, bit-exact
        }
        __syncthreads();
        const float zs = zs_sh;
        float bv = 3.4e38f; int bi = 0;
        #pragma unroll
        for (int jj = 0; jj < 4; ++jj) {
            int j = t + 256 * jj;                // ascending in-thread
            const float* wr = &w[(size_t)j * NC];
            double d0 = 0.0, d1 = 0.0, d2 = 0.0, d3 = 0.0;
            #pragma unroll 8
            for (int k = 0; k < NC; k += 4) {
                float4 wv = *(const float4*)&wr[k];
                d0 += (double)wv.x * zrowd[k];
                d1 += (double)wv.y * zrowd[k + 1];
                d2 += (double)wv.z * zrowd[k + 2];
                d3 += (double)wv.w * zrowd[k + 3];
            }
            double dot = (d0 + d1) + (d2 + d3);
            float mj = (float)dot;               // single round to fp32
            float s1 = zs + wsum[j];             // fl32 add (quantized ~256)
            float dj = s1 - 2.0f * mj;           // fl32 sub
            if (dj < bv) { bv = dj; bi = j; }    // strict < => first index
        }
        rbv[t] = bv; rbi[t] = bi;
        __syncthreads();
        for (int s = 128; s > 0; s >>= 1) {
            if (t < s) {
                float v2 = rbv[t + s]; int i2 = rbi[t + s];
                if (v2 < rbv[t] || (v2 == rbv[t] && i2 < rbi[t])) { rbv[t] = v2; rbi[t] = i2; }
            }
            __syncthreads();
        }
        if (t == 0) idxf[p] = (float)rbi[0];
        __syncthreads();
    }
}

// ---- K2a: counts histogram -> ncs (16 flush atomics per code) --------------
__global__ __launch_bounds__(1024) void hist_kernel(const float* __restrict__ idxf,
                                                    float* __restrict__ ncs) {
    __shared__ int h[NE];
    int t = threadIdx.x;
    h[t] = 0;
    __syncthreads();
    int gid = blockIdx.x * 1024 + t;          // grid 16
    #pragma unroll
    for (int i = 0; i < 4; ++i) {
        int p = gid + i * 16384;
        atomicAdd(&h[(int)idxf[p]], 1);
    }
    __syncthreads();
    if (h[t]) atomicAdd(&ncs[t], (float)h[t]);
}

// ---- K2b: streaming z_q out + loss partials (no hot atomics) ---------------
__global__ __launch_bounds__(256) void out_kernel(const float* __restrict__ z,
                                                  const float* __restrict__ w,
                                                  const float* __restrict__ idxf,
                                                  float* __restrict__ outq,
                                                  float* __restrict__ lpart) {
    const int t   = threadIdx.x;
    const int gid = blockIdx.x * 256 + t;     // grid 1024 -> 262144 threads
    float lsum = 0.0f;
    #pragma unroll
    for (int ch = 0; ch < 4; ++ch) {
        size_t e0 = ((size_t)gid + (size_t)ch * 262144) * 16;
        int b   = (int)(e0 >> 20);
        int hw0 = (int)(e0 & (NHW - 1));
        int c   = (int)((e0 >> 12) & 255);
        int pix0 = (b << 12) + hw0;
        #pragma unroll
        for (int q = 0; q < 4; ++q) {
            float4 zv = *(const float4*)&z[e0 + q * 4];
            float4 ov;
            float* po = &ov.x;
            const float* pz = &zv.x;
            #pragma unroll
            for (int k = 0; k < 4; ++k) {
                int id = (int)idxf[pix0 + q * 4 + k];
                float qv = w[(size_t)id * NC + c];
                po[k] = qv;
                float d = qv - pz[k];
                lsum += d * d;
            }
            *(float4*)&outq[e0 + q * 4] = ov;
        }
    }
    #pragma unroll
    for (int off = 32; off > 0; off >>= 1) lsum += __shfl_down(lsum, off);
    __shared__ float ls[4];
    if ((t & 63) == 0) ls[t >> 6] = lsum;
    __syncthreads();
    if (t == 0) lpart[blockIdx.x] = ls[0] + ls[1] + ls[2] + ls[3];
}

// ---- K2c: dw segmented-sum per channel via LDS; direct nea write -----------
__global__ __launch_bounds__(1024) void dwsum_kernel(const float* __restrict__ z,
                                                     const float* __restrict__ idxf,
                                                     const float* __restrict__ ea,
                                                     float* __restrict__ nea) {
    __shared__ float acc[NE];
    const int c = blockIdx.x;                 // grid 256: one channel per block
    const int t = threadIdx.x;
    acc[t] = 0.0f;
    __syncthreads();
    const float* zc = z + (size_t)c * NHW;    // + b*(NC*NHW) + hw
    #pragma unroll 4
    for (int i = 0; i < 64; ++i) {
        int p  = i * 1024 + t;                // pixel id, coalesced
        int b  = p >> 12;
        int hw = p & (NHW - 1);
        float zv = zc[(size_t)b * (NC * NHW) + hw];
        int id = (int)idxf[p];
        atomicAdd(&acc[id], zv);
    }
    __syncthreads();
    size_t o = (size_t)t * NC + c;            // code t, channel c
    nea[o] = DECAY * ea[o] + (1.0f - DECAY) * acc[t];
}

// ---- K3: finalize ncs EMA, n, cssm, loss from partials ---------------------
__global__ __launch_bounds__(1024) void finalize_kernel(const float* __restrict__ cs,
                                                        const float* __restrict__ lpart,
                                                        float* __restrict__ ncs,
                                                        float* __restrict__ cssm,
                                                        float* __restrict__ loss) {
    int t = threadIdx.x;
    float cnt = ncs[t];
    float v = cs[t] * DECAY + (1.0f - DECAY) * cnt;
    ncs[t] = v;
    __shared__ float red[1024];
    red[t] = v;
    __syncthreads();
    for (int s = 512; s > 0; s >>= 1) {
        if (t < s) red[t] += red[t + s];
        __syncthreads();
    }
    float n = red[0];
    __syncthreads();
    cssm[t] = (v + EPS_) / (n + (float)NE * EPS_) * n;
    red[t] = lpart[t];
    __syncthreads();
    for (int s = 512; s > 0; s >>= 1) {
        if (t < s) red[t] += red[t + s];
        __syncthreads();
    }
    if (t == 0) loss[0] = BETA * red[0] / 16777216.0f;
}

// ---- K4: new_weight = nea / cs_smoothed ------------------------------------
__global__ __launch_bounds__(256) void newweight_kernel(const float* __restrict__ nea,
                                                        const float* __restrict__ cssm,
                                                        float* __restrict__ nw) {
    int lin = blockIdx.x * 256 + threadIdx.x;
    nw[lin] = nea[lin] / cssm[lin >> 8];
}

extern "C" void kernel_launch(void* const* d_in, const int* in_sizes, int n_in,
                              void* d_out, int out_size, void* d_ws, size_t ws_size,
                              hipStream_t stream) {
    const float* z  = (const float*)d_in[0];
    const float* w  = (const float*)d_in[1];
    const float* cs = (const float*)d_in[2];
    const float* ea = (const float*)d_in[3];

    float* out  = (float*)d_out;
    float* loss = out + OFF_LOSS;
    float* idxf = out + OFF_IDXF;
    float* ncs  = out + OFF_NCS;
    float* nea  = out + OFF_NEA;
    float* nw   = out + OFF_NW;

    float* wsf   = (float*)d_ws;
    float* wsum  = wsf;                                        // 1024 f
    float* cssm  = wsf + NE;                                   // 1024 f
    unsigned long long* flags = (unsigned long long*)(wsf + 2 * NE);  // 1024 u64
    float* lpart = wsf + 4 * NE;                               // 1024 f
    int*   cnt   = (int*)(wsf + 5 * NE);                       // 64 f pad
    unsigned short* list = (unsigned short*)(wsf + 5 * NE + 64);  // 65536 u16 (128 KB)

    hipLaunchKernelGGL(init_kernel,      dim3(4),    dim3(256),  0, stream, ncs, cnt);
    hipLaunchKernelGGL(wsum_kernel,      dim3(16),   dim3(64),   0, stream, w, wsum);
    hipLaunchKernelGGL(argmin_kernel,    dim3(1024), dim3(256),  0, stream, z, w, wsum, idxf, flags);
    hipLaunchKernelGGL(gather_kernel,    dim3(256),  dim3(256),  0, stream, flags, list, cnt);
    hipLaunchKernelGGL(fixup2_kernel,    dim3(2048), dim3(256),  0, stream, z, w, wsum, list, cnt, idxf);
    hipLaunchKernelGGL(hist_kernel,      dim3(16),   dim3(1024), 0, stream, idxf, ncs);
    hipLaunchKernelGGL(out_kernel,       dim3(1024), dim3(256),  0, stream, z, w, idxf, out, lpart);
    hipLaunchKernelGGL(dwsum_kernel,     dim3(256),  dim3(1024), 0, stream, z, idxf, ea, nea);
    hipLaunchKernelGGL(finalize_kernel,  dim3(1),    dim3(1024), 0, stream, cs, lpart, ncs, cssm, loss);
    hipLaunchKernelGGL(newweight_kernel, dim3(1024), dim3(256),  0, stream, nea, cssm, nw);
}

// Round 9
// 585.581 us; speedup vs baseline: 4.1738x; 1.7205x over previous
//
#include <hip/hip_runtime.h>
#include <hip/hip_bf16.h>

typedef unsigned short ushort_t;
typedef __attribute__((ext_vector_type(8))) short short8;
typedef __attribute__((ext_vector_type(4))) float f32x4;

// Problem constants
#define NB    16
#define NC    256
#define NHW   4096
#define NPIX  65536
#define NE    1024
#define BETA  0.25f
#define DECAY 0.99f
#define EPS_  1e-5f
#define GAP_FLAG 1.25e-4f

// d_out layout (floats)
#define OFF_LOSS 16777216
#define OFF_IDXF 16777217
#define OFF_NCS  16842753
#define OFF_NEA  16843777
#define OFF_NW   17105921

// ws layout (float offsets)
#define WS_WSUM  0
#define WS_CSSM  1024
#define WS_LPART 2048
#define WS_CNT   3072
#define WS_FLAGS 3104
#define WS_LIST  5152
#define WS_WHI   40960
#define WS_WLO   (WS_WHI + 131072)
#define WS_ZHI   (WS_WLO + 131072)
#define WS_ZLO   (WS_ZHI + 8388608)
#define WS_BV8   (WS_ZLO + 8388608)
#define WS_SV8   (WS_BV8 + 524288)
#define WS_BJ8   (WS_SV8 + 524288)
#define WS_END   (WS_BJ8 + 524288)

__device__ __forceinline__ float sq_nofma(float x) {
    float s = x * x;
    asm volatile("" : "+v"(s));
    return s;
}

__device__ __forceinline__ float np_pair128_sq(const float* __restrict__ a) {
    float r[8];
    #pragma unroll
    for (int m = 0; m < 8; ++m) r[m] = sq_nofma(a[m]);
    for (int i = 8; i < 128; i += 8) {
        #pragma unroll
        for (int m = 0; m < 8; ++m) r[m] += sq_nofma(a[i + m]);
    }
    return ((r[0] + r[1]) + (r[2] + r[3])) + ((r[4] + r[5]) + (r[6] + r[7]));
}

__device__ __forceinline__ void bf16split(float x, ushort_t& h, ushort_t& l) {
    unsigned u = __float_as_uint(x);
    unsigned hb = (u + 0x7FFFu + ((u >> 16) & 1u)) >> 16;       // RTN-even
    float hf = __uint_as_float(hb << 16);
    float lof = x - hf;
    unsigned u2 = __float_as_uint(lof);
    unsigned lb = (u2 + 0x7FFFu + ((u2 >> 16) & 1u)) >> 16;
    h = (ushort_t)hb; l = (ushort_t)lb;
}

__device__ __forceinline__ void gload16(const void* g, void* ldsp) {
    __builtin_amdgcn_global_load_lds((const __attribute__((address_space(1))) unsigned int*)g,
                                     (__attribute__((address_space(3))) unsigned int*)ldsp,
                                     16, 0, 0);
}

// ---- K0a: zero counts accumulator + list counter ---------------------------
__global__ __launch_bounds__(256) void init_kernel(float* __restrict__ ncs,
                                                   int* __restrict__ cnt) {
    int gid = blockIdx.x * 256 + threadIdx.x;
    if (gid < NE) ncs[gid] = 0.0f;
    if (gid == 0) cnt[0] = 0;
}

// ---- K0b: wsum[j] = np.float32 pairwise sum of w[j][:]^2 -------------------
__global__ __launch_bounds__(64) void wsum_kernel(const float* __restrict__ w,
                                                  float* __restrict__ wsum) {
    int j = blockIdx.x * 64 + threadIdx.x;
    const float* wr = w + (size_t)j * NC;
    wsum[j] = np_pair128_sq(wr) + np_pair128_sq(wr + 128);
}

// ---- P1: pack w -> whi/wlo bf16 [1024][256] --------------------------------
__global__ __launch_bounds__(256) void wpack_kernel(const float* __restrict__ w,
                                                    ushort_t* __restrict__ whi,
                                                    ushort_t* __restrict__ wlo) {
    int c = blockIdx.x, k = threadIdx.x;
    ushort_t h, l;
    bf16split(w[c * NC + k], h, l);
    whi[c * NC + k] = h;
    wlo[c * NC + k] = l;
}

// ---- P2: pack z -> zhi/zlo bf16 [65536 pix][256 k] (LDS transpose) ---------
__global__ __launch_bounds__(256) void zpack_kernel(const float* __restrict__ z,
                                                    ushort_t* __restrict__ zhi,
                                                    ushort_t* __restrict__ zlo) {
    __shared__ float zs[64 * 65];
    const int t = threadIdx.x;
    const int P0 = blockIdx.x * 64;
    const int b = P0 >> 12, hw0 = P0 & (NHW - 1);
    const int K0 = blockIdx.y * 64;
    const int hw = t & 63, cq = t >> 6;
    const float* zb = z + (size_t)b * (NC * NHW) + hw0 + hw;
    #pragma unroll
    for (int i = 0; i < 16; ++i) {
        int kl = cq * 16 + i;
        zs[hw * 65 + kl] = zb[(size_t)(K0 + kl) * NHW];
    }
    __syncthreads();
    const int p = t >> 2, kq = t & 3;
    size_t obase = (size_t)(P0 + p) * NC + K0 + kq * 16;
    #pragma unroll
    for (int h2 = 0; h2 < 2; ++h2) {
        unsigned hi4[4], lo4[4];
        #pragma unroll
        for (int j2 = 0; j2 < 4; ++j2) {
            ushort_t ha, la, hb, lb;
            bf16split(zs[p * 65 + kq * 16 + h2 * 8 + j2 * 2],     ha, la);
            bf16split(zs[p * 65 + kq * 16 + h2 * 8 + j2 * 2 + 1], hb, lb);
            hi4[j2] = (unsigned)ha | ((unsigned)hb << 16);
            lo4[j2] = (unsigned)la | ((unsigned)lb << 16);
        }
        *(uint4*)&zhi[obase + h2 * 8] = make_uint4(hi4[0], hi4[1], hi4[2], hi4[3]);
        *(uint4*)&zlo[obase + h2 * 8] = make_uint4(lo4[0], lo4[1], lo4[2], lo4[3]);
    }
}

// ---- K1: MFMA distance GEMM + per-tile top-2 argmin ------------------------
// A = codes (128/tile), B = pixels (128/tile), K = 256 in 8 steps of 32.
// dot = zh*wh + zh*wl + zl*wh; score = wsum - 2*dot.
// Wave (wc,wp) covers codes wc*64.. and pixels wp*64..; cross-wave merge via
// LDS fixes the round-8 race (both wc waves wrote the same pixel slot).
__global__ __launch_bounds__(256) void gemm_kernel(const ushort_t* __restrict__ whi,
                                                   const ushort_t* __restrict__ wlo,
                                                   const ushort_t* __restrict__ zhi,
                                                   const ushort_t* __restrict__ zlo,
                                                   const float* __restrict__ wsum,
                                                   float* __restrict__ bv8,
                                                   float* __restrict__ sv8,
                                                   int* __restrict__ bj8) {
    __shared__ __align__(16) short lds[16384];  // Ahi|Alo|Bhi|Blo [128][32] each
    const int t = threadIdx.x;
    const int l = t & 63;
    const int w = t >> 6;
    const int P0 = blockIdx.x * 128;
    const int C0 = blockIdx.y * 128;
    const int wc = w >> 1, wp = w & 1;

    const ushort_t* srcb;
    int row0;
    if (w == 0)      { srcb = whi; row0 = C0; }
    else if (w == 1) { srcb = wlo; row0 = C0; }
    else if (w == 2) { srcb = zhi; row0 = P0; }
    else             { srcb = zlo; row0 = P0; }
    const int lrow = l >> 2, lk = (l & 3) * 8;

    f32x4 acc[4][4];
    #pragma unroll
    for (int m = 0; m < 4; ++m)
        #pragma unroll
        for (int n = 0; n < 4; ++n)
            #pragma unroll
            for (int e = 0; e < 4; ++e) acc[m][n][e] = 0.0f;

    for (int ks = 0; ks < 8; ++ks) {
        if (ks) __syncthreads();
        const ushort_t* s0 = srcb + (size_t)(row0 + lrow) * NC + ks * 32 + lk;
        #pragma unroll
        for (int i = 0; i < 8; ++i)
            gload16(s0 + i * 16 * NC, &lds[w * 4096 + i * 512]);
        __syncthreads();

        short8 ah[4], al[4], bh[4], bl[4];
        #pragma unroll
        for (int m = 0; m < 4; ++m) {
            int r = (wc * 64 + m * 16 + (l & 15)) * 32 + (l >> 4) * 8;
            ah[m] = *(const short8*)&lds[r];
            al[m] = *(const short8*)&lds[4096 + r];
        }
        #pragma unroll
        for (int n = 0; n < 4; ++n) {
            int r = (wp * 64 + n * 16 + (l & 15)) * 32 + (l >> 4) * 8;
            bh[n] = *(const short8*)&lds[8192 + r];
            bl[n] = *(const short8*)&lds[12288 + r];
        }
        #pragma unroll
        for (int m = 0; m < 4; ++m)
            #pragma unroll
            for (int n = 0; n < 4; ++n) {
                acc[m][n] = __builtin_amdgcn_mfma_f32_16x16x32_bf16(ah[m], bh[n], acc[m][n], 0, 0, 0);
                acc[m][n] = __builtin_amdgcn_mfma_f32_16x16x32_bf16(ah[m], bl[n], acc[m][n], 0, 0, 0);
                acc[m][n] = __builtin_amdgcn_mfma_f32_16x16x32_bf16(al[m], bh[n], acc[m][n], 0, 0, 0);
            }
    }

    // epilogue: per-pixel top-2 over this wave's 64 codes
    float en[4][4];
    #pragma unroll
    for (int m = 0; m < 4; ++m)
        #pragma unroll
        for (int r = 0; r < 4; ++r)
            en[m][r] = wsum[C0 + wc * 64 + m * 16 + (l >> 4) * 4 + r];

    __syncthreads();                       // staging LDS no longer read
    float* bvx = (float*)lds;              // [2 wc][128 px]
    float* svx = bvx + 256;
    int*   bix = (int*)(svx + 256);

    #pragma unroll
    for (int n = 0; n < 4; ++n) {
        float bv = 3.4e38f, sv = 3.4e38f;
        int bi = 0;
        #pragma unroll
        for (int m = 0; m < 4; ++m)
            #pragma unroll
            for (int r = 0; r < 4; ++r) {
                float s = en[m][r] - 2.0f * acc[m][n][r];
                int code = C0 + wc * 64 + m * 16 + (l >> 4) * 4 + r;
                if (s < bv) { sv = bv; bv = s; bi = code; }     // ascending codes in-lane
                else if (s < sv) sv = s;
            }
        #pragma unroll
        for (int x = 16; x <= 32; x <<= 1) {
            float v2 = __shfl_xor(bv, x);
            float s2 = __shfl_xor(sv, x);
            int   i2 = __shfl_xor(bi, x);
            if (v2 < bv || (v2 == bv && i2 < bi)) { sv = fminf(bv, s2); bv = v2; bi = i2; }
            else sv = fminf(sv, v2);
        }
        if ((l >> 4) == 0) {
            int lp = wp * 64 + n * 16 + l;
            bvx[wc * 128 + lp] = bv;
            svx[wc * 128 + lp] = sv;
            bix[wc * 128 + lp] = bi;
        }
    }
    __syncthreads();
    if (t < 128) {                          // merge the two code-halves
        float bv = bvx[t], sv = svx[t];
        int bi = bix[t];
        float v2 = bvx[128 + t], s2 = svx[128 + t];
        int i2 = bix[128 + t];
        if (v2 < bv || (v2 == bv && i2 < bi)) { sv = fminf(bv, s2); bv = v2; bi = i2; }
        else sv = fminf(sv, v2);
        int o = blockIdx.y * NPIX + P0 + t;
        bv8[o] = bv; sv8[o] = sv; bj8[o] = bi;
    }
}

// ---- K1c: combine 8 code-tile triples -> idx + fixup list ------------------
__global__ __launch_bounds__(256) void combine_kernel(const float* __restrict__ bv8,
                                                      const float* __restrict__ sv8,
                                                      const int* __restrict__ bj8,
                                                      float* __restrict__ idxf,
                                                      ushort_t* __restrict__ list,
                                                      int* __restrict__ cnt) {
    int pix = blockIdx.x * 256 + threadIdx.x;
    float bv = bv8[pix], sv = sv8[pix];
    int bi = bj8[pix];
    #pragma unroll
    for (int ct = 1; ct < 8; ++ct) {
        float v2 = bv8[ct * NPIX + pix];
        float s2 = sv8[ct * NPIX + pix];
        int   i2 = bj8[ct * NPIX + pix];
        if (v2 < bv || (v2 == bv && i2 < bi)) { sv = fminf(bv, s2); bv = v2; bi = i2; }
        else sv = fminf(sv, v2);
    }
    idxf[pix] = (float)bi;
    if (sv - bv < GAP_FLAG) {
        int pos = atomicAdd(cnt, 1);
        list[pos] = (ushort_t)pix;
    }
}

// ================== FALLBACK PATH (round-7 argmin), used if ws too small ====
__global__ __launch_bounds__(256) void argmin_kernel(const float* __restrict__ z,
                                                     const float* __restrict__ w,
                                                     const float* __restrict__ enorm,
                                                     float* __restrict__ idxf,
                                                     unsigned long long* __restrict__ flags) {
    __shared__ __align__(16) float smem[64 * 68 + 128 * 68];
    float* zt = smem;
    float* wt = smem + 64 * 68;
    const int t = threadIdx.x;
    const int pr = t & 7;
    const int cr = t >> 3;
    const int P0 = blockIdx.x * 64;
    const int b = P0 >> 12;
    const int hw0 = P0 & (NHW - 1);
    const float* zb = z + (size_t)b * (NC * NHW) + hw0;
    float bestv[8], secv[8];
    int besti[8];
    #pragma unroll
    for (int i = 0; i < 8; ++i) { bestv[i] = 3.4e38f; secv[i] = 3.4e38f; besti[i] = 0; }
    for (int cc = 0; cc < 8; ++cc) {
        float acc[8][4];
        #pragma unroll
        for (int i = 0; i < 8; ++i)
            #pragma unroll
            for (int j = 0; j < 4; ++j) acc[i][j] = 0.0f;
        for (int kc = 0; kc < 4; ++kc) {
            {
                int p = t & 63;
                int k0 = (t >> 6) * 16;
                int f2 = ((p >> 3) & 3) << 2;
                #pragma unroll
                for (int i = 0; i < 16; ++i) {
                    int k = k0 + i;
                    zt[p * 68 + (k ^ f2)] = zb[(size_t)(kc * 64 + k) * NHW + p];
                }
            }
            {
                #pragma unroll
                for (int i = 0; i < 8; ++i) {
                    int f = t + 256 * i;
                    int jj = f >> 4;
                    int k4 = f & 15;
                    float4 v = *(const float4*)&w[(size_t)(cc * 128 + jj) * NC + kc * 64 + k4 * 4];
                    *(float4*)&wt[jj * 68 + k4 * 4] = v;
                }
            }
            __syncthreads();
            #pragma unroll 2
            for (int k = 0; k < 64; k += 4) {
                float4 za[8], wb[4];
                #pragma unroll
                for (int i = 0; i < 8; ++i)
                    za[i] = *(float4*)&zt[(pr + 8 * i) * 68 + (k ^ ((i & 3) << 2))];
                #pragma unroll
                for (int j = 0; j < 4; ++j)
                    wb[j] = *(float4*)&wt[(cr + 32 * j) * 68 + k];
                #pragma unroll
                for (int i = 0; i < 8; ++i)
                    #pragma unroll
                    for (int j = 0; j < 4; ++j)
                        acc[i][j] += za[i].x * wb[j].x + za[i].y * wb[j].y +
                                     za[i].z * wb[j].z + za[i].w * wb[j].w;
            }
            __syncthreads();
        }
        #pragma unroll
        for (int j = 0; j < 4; ++j) {
            int code = cc * 128 + cr + 32 * j;
            float enj = enorm[code];
            #pragma unroll
            for (int i = 0; i < 8; ++i) {
                float s = enj - 2.0f * acc[i][j];
                if (s < bestv[i]) { secv[i] = bestv[i]; bestv[i] = s; besti[i] = code; }
                else if (s < secv[i]) secv[i] = s;
            }
        }
    }
    float* rv = smem;
    int* ri = (int*)(smem + 2048);
    float* rs = smem + 4096;
    #pragma unroll
    for (int i = 0; i < 8; ++i) {
        int p = pr + 8 * i;
        rv[p * 32 + cr] = bestv[i];
        ri[p * 32 + cr] = besti[i];
        rs[p * 32 + cr] = secv[i];
    }
    __syncthreads();
    if (t < 64) {
        int p = t;
        float bv = rv[p * 32], sv = rs[p * 32];
        int bi = ri[p * 32];
        for (int s2 = 1; s2 < 32; ++s2) {
            float v = rv[p * 32 + s2];
            float v2 = rs[p * 32 + s2];
            int ii = ri[p * 32 + s2];
            if (v < bv) { sv = bv; bv = v; bi = ii; }
            else {
                if (v < sv) sv = v;
                if (v == bv && ii < bi) bi = ii;
            }
            if (v2 < sv) sv = v2;
        }
        idxf[P0 + p] = (float)bi;
        unsigned long long mask = __ballot((sv - bv) < GAP_FLAG);
        if (t == 0) flags[blockIdx.x] = mask;
    }
}

__global__ __launch_bounds__(256) void gather_kernel(const unsigned long long* __restrict__ flags,
                                                     ushort_t* __restrict__ list,
                                                     int* __restrict__ cnt) {
    int p = blockIdx.x * 256 + threadIdx.x;
    unsigned long long m = flags[p >> 6];
    if ((m >> (p & 63)) & 1ULL) {
        int pos = atomicAdd(cnt, 1);
        list[pos] = (ushort_t)p;
    }
}
// ================== end fallback ============================================

// ---- K1b: np-fp32-mimic re-argmin, one block per flagged pixel -------------
__global__ __launch_bounds__(256) void fixup2_kernel(const float* __restrict__ z,
                                                     const float* __restrict__ w,
                                                     const float* __restrict__ wsum,
                                                     const ushort_t* __restrict__ list,
                                                     const int* __restrict__ cnt,
                                                     float* __restrict__ idxf) {
    const int count = cnt[0];
    const int t = threadIdx.x;
    __shared__ float zrowf[NC];
    __shared__ double zrowd[NC];
    __shared__ float zs_sh;
    __shared__ float rbv[256];
    __shared__ int rbi[256];
    for (int i = blockIdx.x; i < count; i += gridDim.x) {
        int p = list[i];
        int b = p >> 12;
        int hw = p & (NHW - 1);
        float zv = z[(size_t)b * (NC * NHW) + (size_t)t * NHW + hw];
        zrowf[t] = zv;
        zrowd[t] = (double)zv;
        __syncthreads();
        if (t == 0) zs_sh = np_pair128_sq(zrowf) + np_pair128_sq(zrowf + 128);
        __syncthreads();
        const float zs = zs_sh;
        float bv = 3.4e38f;
        int bi = 0;
        #pragma unroll
        for (int jj = 0; jj < 4; ++jj) {
            int j = t + 256 * jj;
            const float* wr = &w[(size_t)j * NC];
            double d0 = 0.0, d1 = 0.0, d2 = 0.0, d3 = 0.0;
            #pragma unroll 8
            for (int k = 0; k < NC; k += 4) {
                float4 wv = *(const float4*)&wr[k];
                d0 += (double)wv.x * zrowd[k];
                d1 += (double)wv.y * zrowd[k + 1];
                d2 += (double)wv.z * zrowd[k + 2];
                d3 += (double)wv.w * zrowd[k + 3];
            }
            double dot = (d0 + d1) + (d2 + d3);
            float mj = (float)dot;
            float s1 = zs + wsum[j];
            float dj = s1 - 2.0f * mj;
            if (dj < bv) { bv = dj; bi = j; }
        }
        rbv[t] = bv; rbi[t] = bi;
        __syncthreads();
        for (int s = 128; s > 0; s >>= 1) {
            if (t < s) {
                float v2 = rbv[t + s];
                int i2 = rbi[t + s];
                if (v2 < rbv[t] || (v2 == rbv[t] && i2 < rbi[t])) { rbv[t] = v2; rbi[t] = i2; }
            }
            __syncthreads();
        }
        if (t == 0) idxf[p] = (float)rbi[0];
        __syncthreads();
    }
}

// ---- K2a: counts histogram -> ncs ------------------------------------------
__global__ __launch_bounds__(1024) void hist_kernel(const float* __restrict__ idxf,
                                                    float* __restrict__ ncs) {
    __shared__ int h[NE];
    int t = threadIdx.x;
    h[t] = 0;
    __syncthreads();
    int gid = blockIdx.x * 1024 + t;
    #pragma unroll
    for (int i = 0; i < 4; ++i) atomicAdd(&h[(int)idxf[gid + i * 16384]], 1);
    __syncthreads();
    if (h[t]) atomicAdd(&ncs[t], (float)h[t]);
}

// ---- K2b: streaming z_q out + loss partials --------------------------------
__global__ __launch_bounds__(256) void out_kernel(const float* __restrict__ z,
                                                  const float* __restrict__ w,
                                                  const float* __restrict__ idxf,
                                                  float* __restrict__ outq,
                                                  float* __restrict__ lpart) {
    const int t = threadIdx.x;
    const int gid = blockIdx.x * 256 + t;
    float lsum = 0.0f;
    #pragma unroll
    for (int ch = 0; ch < 4; ++ch) {
        size_t e0 = ((size_t)gid + (size_t)ch * 262144) * 16;
        int hw0 = (int)(e0 & (NHW - 1));
        int c = (int)((e0 >> 12) & 255);
        int b = (int)(e0 >> 20);
        int pix0 = (b << 12) + hw0;
        #pragma unroll
        for (int q = 0; q < 4; ++q) {
            float4 zv = *(const float4*)&z[e0 + q * 4];
            float4 ov;
            float* po = &ov.x;
            const float* pz = &zv.x;
            #pragma unroll
            for (int k = 0; k < 4; ++k) {
                int id = (int)idxf[pix0 + q * 4 + k];
                float qv = w[(size_t)id * NC + c];
                po[k] = qv;
                float d = qv - pz[k];
                lsum += d * d;
            }
            *(float4*)&outq[e0 + q * 4] = ov;
        }
    }
    #pragma unroll
    for (int off = 32; off > 0; off >>= 1) lsum += __shfl_down(lsum, off);
    __shared__ float ls[4];
    if ((t & 63) == 0) ls[t >> 6] = lsum;
    __syncthreads();
    if (t == 0) lpart[blockIdx.x] = ls[0] + ls[1] + ls[2] + ls[3];
}

// ---- K2c: dw segmented-sum per channel via LDS -----------------------------
__global__ __launch_bounds__(1024) void dwsum_kernel(const float* __restrict__ z,
                                                     const float* __restrict__ idxf,
                                                     const float* __restrict__ ea,
                                                     float* __restrict__ nea) {
    __shared__ float acc[NE];
    const int c = blockIdx.x;
    const int t = threadIdx.x;
    acc[t] = 0.0f;
    __syncthreads();
    const float* zc = z + (size_t)c * NHW;
    #pragma unroll 4
    for (int i = 0; i < 64; ++i) {
        int p = i * 1024 + t;
        int b = p >> 12;
        int hw = p & (NHW - 1);
        float zv = zc[(size_t)b * (NC * NHW) + hw];
        atomicAdd(&acc[(int)idxf[p]], zv);
    }
    __syncthreads();
    size_t o = (size_t)t * NC + c;
    nea[o] = DECAY * ea[o] + (1.0f - DECAY) * acc[t];
}

// ---- K3: finalize ----------------------------------------------------------
__global__ __launch_bounds__(1024) void finalize_kernel(const float* __restrict__ cs,
                                                        const float* __restrict__ lpart,
                                                        float* __restrict__ ncs,
                                                        float* __restrict__ cssm,
                                                        float* __restrict__ loss) {
    int t = threadIdx.x;
    float cnt = ncs[t];
    float v = cs[t] * DECAY + (1.0f - DECAY) * cnt;
    ncs[t] = v;
    __shared__ float red[1024];
    red[t] = v;
    __syncthreads();
    for (int s = 512; s > 0; s >>= 1) {
        if (t < s) red[t] += red[t + s];
        __syncthreads();
    }
    float n = red[0];
    __syncthreads();
    cssm[t] = (v + EPS_) / (n + (float)NE * EPS_) * n;
    red[t] = lpart[t];
    __syncthreads();
    for (int s = 512; s > 0; s >>= 1) {
        if (t < s) red[t] += red[t + s];
        __syncthreads();
    }
    if (t == 0) loss[0] = BETA * red[0] / 16777216.0f;
}

// ---- K4: new_weight --------------------------------------------------------
__global__ __launch_bounds__(256) void newweight_kernel(const float* __restrict__ nea,
                                                        const float* __restrict__ cssm,
                                                        float* __restrict__ nw) {
    int lin = blockIdx.x * 256 + threadIdx.x;
    nw[lin] = nea[lin] / cssm[lin >> 8];
}

extern "C" void kernel_launch(void* const* d_in, const int* in_sizes, int n_in,
                              void* d_out, int out_size, void* d_ws, size_t ws_size,
                              hipStream_t stream) {
    const float* z  = (const float*)d_in[0];
    const float* w  = (const float*)d_in[1];
    const float* cs = (const float*)d_in[2];
    const float* ea = (const float*)d_in[3];

    float* out  = (float*)d_out;
    float* loss = out + OFF_LOSS;
    float* idxf = out + OFF_IDXF;
    float* ncs  = out + OFF_NCS;
    float* nea  = out + OFF_NEA;
    float* nw   = out + OFF_NW;

    float* wsf = (float*)d_ws;
    float* wsum = wsf + WS_WSUM;
    float* cssm = wsf + WS_CSSM;
    float* lpart = wsf + WS_LPART;
    int* cnt = (int*)(wsf + WS_CNT);
    unsigned long long* flags = (unsigned long long*)(wsf + WS_FLAGS);
    ushort_t* list = (ushort_t*)(wsf + WS_LIST);

    hipLaunchKernelGGL(init_kernel, dim3(4), dim3(256), 0, stream, ncs, cnt);
    hipLaunchKernelGGL(wsum_kernel, dim3(16), dim3(64), 0, stream, w, wsum);

    if (ws_size >= (size_t)WS_END * 4) {
        // fast path: bf16-split MFMA GEMM
        ushort_t* whi = (ushort_t*)(wsf + WS_WHI);
        ushort_t* wlo = (ushort_t*)(wsf + WS_WLO);
        ushort_t* zhi = (ushort_t*)(wsf + WS_ZHI);
        ushort_t* zlo = (ushort_t*)(wsf + WS_ZLO);
        float* bv8 = wsf + WS_BV8;
        float* sv8 = wsf + WS_SV8;
        int* bj8 = (int*)(wsf + WS_BJ8);

        hipLaunchKernelGGL(wpack_kernel, dim3(1024), dim3(256), 0, stream, w, whi, wlo);
        hipLaunchKernelGGL(zpack_kernel, dim3(1024, 4), dim3(256), 0, stream, z, zhi, zlo);
        hipLaunchKernelGGL(gemm_kernel, dim3(512, 8), dim3(256), 0, stream,
                           whi, wlo, zhi, zlo, wsum, bv8, sv8, bj8);
        hipLaunchKernelGGL(combine_kernel, dim3(256), dim3(256), 0, stream,
                           bv8, sv8, bj8, idxf, list, cnt);
    } else {
        // fallback: round-7 fp32 VALU argmin
        hipLaunchKernelGGL(argmin_kernel, dim3(1024), dim3(256), 0, stream, z, w, wsum, idxf, flags);
        hipLaunchKernelGGL(gather_kernel, dim3(256), dim3(256), 0, stream, flags, list, cnt);
    }

    hipLaunchKernelGGL(fixup2_kernel, dim3(2048), dim3(256), 0, stream, z, w, wsum, list, cnt, idxf);
    hipLaunchKernelGGL(hist_kernel, dim3(16), dim3(1024), 0, stream, idxf, ncs);
    hipLaunchKernelGGL(out_kernel, dim3(1024), dim3(256), 0, stream, z, w, idxf, out, lpart);
    hipLaunchKernelGGL(dwsum_kernel, dim3(256), dim3(1024), 0, stream, z, idxf, ea, nea);
    hipLaunchKernelGGL(finalize_kernel, dim3(1), dim3(1024), 0, stream, cs, lpart, ncs, cssm, loss);
    hipLaunchKernelGGL(newweight_kernel, dim3(1024), dim3(256), 0, stream, nea, cssm, nw);
}

// Round 10
// 429.081 us; speedup vs baseline: 5.6962x; 1.3647x over previous
//
#include <hip/hip_runtime.h>
#include <hip/hip_bf16.h>

typedef unsigned short ushort_t;
typedef __attribute__((ext_vector_type(8))) short short8;
typedef __attribute__((ext_vector_type(4))) float f32x4;

// Problem constants
#define NB    16
#define NC    256
#define NHW   4096
#define NPIX  65536
#define NE    1024
#define BETA  0.25f
#define DECAY 0.99f
#define EPS_  1e-5f
#define GAP_FLAG 1.25e-4f

// d_out layout (floats)
#define OFF_LOSS 16777216
#define OFF_IDXF 16777217
#define OFF_NCS  16842753
#define OFF_NEA  16843777
#define OFF_NW   17105921

// ws layout (float offsets)
#define WS_WSUM  0
#define WS_CSSM  1024
#define WS_LPART 2048
#define WS_CNT   3072
#define WS_FLAGS 3104
#define WS_LIST  5152
#define WS_WHI   40960
#define WS_WLO   (WS_WHI + 131072)
#define WS_ZHI   (WS_WLO + 131072)
#define WS_ZLO   (WS_ZHI + 8388608)
#define WS_BV8   (WS_ZLO + 8388608)
#define WS_SV8   (WS_BV8 + 524288)
#define WS_BJ8   (WS_SV8 + 524288)
#define WS_END   (WS_BJ8 + 524288)

__device__ __forceinline__ float sq_nofma(float x) {
    float s = x * x;
    asm volatile("" : "+v"(s));
    return s;
}

__device__ __forceinline__ float np_pair128_sq(const float* __restrict__ a) {
    float r[8];
    #pragma unroll
    for (int m = 0; m < 8; ++m) r[m] = sq_nofma(a[m]);
    for (int i = 8; i < 128; i += 8) {
        #pragma unroll
        for (int m = 0; m < 8; ++m) r[m] += sq_nofma(a[i + m]);
    }
    return ((r[0] + r[1]) + (r[2] + r[3])) + ((r[4] + r[5]) + (r[6] + r[7]));
}

__device__ __forceinline__ void bf16split(float x, ushort_t& h, ushort_t& l) {
    unsigned u = __float_as_uint(x);
    unsigned hb = (u + 0x7FFFu + ((u >> 16) & 1u)) >> 16;       // RTN-even
    float hf = __uint_as_float(hb << 16);
    float lof = x - hf;
    unsigned u2 = __float_as_uint(lof);
    unsigned lb = (u2 + 0x7FFFu + ((u2 >> 16) & 1u)) >> 16;
    h = (ushort_t)hb; l = (ushort_t)lb;
}

__device__ __forceinline__ void gload16(const void* g, void* ldsp) {
    __builtin_amdgcn_global_load_lds((const __attribute__((address_space(1))) unsigned int*)g,
                                     (__attribute__((address_space(3))) unsigned int*)ldsp,
                                     16, 0, 0);
}

// ---- K0a: zero counts accumulator + list counter ---------------------------
__global__ __launch_bounds__(256) void init_kernel(float* __restrict__ ncs,
                                                   int* __restrict__ cnt) {
    int gid = blockIdx.x * 256 + threadIdx.x;
    if (gid < NE) ncs[gid] = 0.0f;
    if (gid == 0) cnt[0] = 0;
}

// ---- K0b: wsum[j] = np.float32 pairwise sum of w[j][:]^2 -------------------
__global__ __launch_bounds__(64) void wsum_kernel(const float* __restrict__ w,
                                                  float* __restrict__ wsum) {
    int j = blockIdx.x * 64 + threadIdx.x;
    const float* wr = w + (size_t)j * NC;
    wsum[j] = np_pair128_sq(wr) + np_pair128_sq(wr + 128);
}

// ---- P1: pack w -> whi/wlo bf16 [1024][256] --------------------------------
__global__ __launch_bounds__(256) void wpack_kernel(const float* __restrict__ w,
                                                    ushort_t* __restrict__ whi,
                                                    ushort_t* __restrict__ wlo) {
    int c = blockIdx.x, k = threadIdx.x;
    ushort_t h, l;
    bf16split(w[c * NC + k], h, l);
    whi[c * NC + k] = h;
    wlo[c * NC + k] = l;
}

// ---- P2: pack z -> zhi/zlo bf16 [65536 pix][256 k] (LDS transpose) ---------
__global__ __launch_bounds__(256) void zpack_kernel(const float* __restrict__ z,
                                                    ushort_t* __restrict__ zhi,
                                                    ushort_t* __restrict__ zlo) {
    __shared__ float zs[64 * 65];
    const int t = threadIdx.x;
    const int P0 = blockIdx.x * 64;
    const int b = P0 >> 12, hw0 = P0 & (NHW - 1);
    const int K0 = blockIdx.y * 64;
    const int hw = t & 63, cq = t >> 6;
    const float* zb = z + (size_t)b * (NC * NHW) + hw0 + hw;
    #pragma unroll
    for (int i = 0; i < 16; ++i) {
        int kl = cq * 16 + i;
        zs[hw * 65 + kl] = zb[(size_t)(K0 + kl) * NHW];
    }
    __syncthreads();
    const int p = t >> 2, kq = t & 3;
    size_t obase = (size_t)(P0 + p) * NC + K0 + kq * 16;
    #pragma unroll
    for (int h2 = 0; h2 < 2; ++h2) {
        unsigned hi4[4], lo4[4];
        #pragma unroll
        for (int j2 = 0; j2 < 4; ++j2) {
            ushort_t ha, la, hb, lb;
            bf16split(zs[p * 65 + kq * 16 + h2 * 8 + j2 * 2],     ha, la);
            bf16split(zs[p * 65 + kq * 16 + h2 * 8 + j2 * 2 + 1], hb, lb);
            hi4[j2] = (unsigned)ha | ((unsigned)hb << 16);
            lo4[j2] = (unsigned)la | ((unsigned)lb << 16);
        }
        *(uint4*)&zhi[obase + h2 * 8] = make_uint4(hi4[0], hi4[1], hi4[2], hi4[3]);
        *(uint4*)&zlo[obase + h2 * 8] = make_uint4(lo4[0], lo4[1], lo4[2], lo4[3]);
    }
}

// ---- K1: MFMA distance GEMM + per-tile top-2 argmin ------------------------
__global__ __launch_bounds__(256) void gemm_kernel(const ushort_t* __restrict__ whi,
                                                   const ushort_t* __restrict__ wlo,
                                                   const ushort_t* __restrict__ zhi,
                                                   const ushort_t* __restrict__ zlo,
                                                   const float* __restrict__ wsum,
                                                   float* __restrict__ bv8,
                                                   float* __restrict__ sv8,
                                                   int* __restrict__ bj8) {
    __shared__ __align__(16) short lds[16384];  // Ahi|Alo|Bhi|Blo [128][32] each
    const int t = threadIdx.x;
    const int l = t & 63;
    const int w = t >> 6;
    const int P0 = blockIdx.x * 128;
    const int C0 = blockIdx.y * 128;
    const int wc = w >> 1, wp = w & 1;

    const ushort_t* srcb;
    int row0;
    if (w == 0)      { srcb = whi; row0 = C0; }
    else if (w == 1) { srcb = wlo; row0 = C0; }
    else if (w == 2) { srcb = zhi; row0 = P0; }
    else             { srcb = zlo; row0 = P0; }
    const int lrow = l >> 2, lk = (l & 3) * 8;

    f32x4 acc[4][4];
    #pragma unroll
    for (int m = 0; m < 4; ++m)
        #pragma unroll
        for (int n = 0; n < 4; ++n)
            #pragma unroll
            for (int e = 0; e < 4; ++e) acc[m][n][e] = 0.0f;

    for (int ks = 0; ks < 8; ++ks) {
        if (ks) __syncthreads();
        const ushort_t* s0 = srcb + (size_t)(row0 + lrow) * NC + ks * 32 + lk;
        #pragma unroll
        for (int i = 0; i < 8; ++i)
            gload16(s0 + i * 16 * NC, &lds[w * 4096 + i * 512]);
        __syncthreads();

        short8 ah[4], al[4], bh[4], bl[4];
        #pragma unroll
        for (int m = 0; m < 4; ++m) {
            int r = (wc * 64 + m * 16 + (l & 15)) * 32 + (l >> 4) * 8;
            ah[m] = *(const short8*)&lds[r];
            al[m] = *(const short8*)&lds[4096 + r];
        }
        #pragma unroll
        for (int n = 0; n < 4; ++n) {
            int r = (wp * 64 + n * 16 + (l & 15)) * 32 + (l >> 4) * 8;
            bh[n] = *(const short8*)&lds[8192 + r];
            bl[n] = *(const short8*)&lds[12288 + r];
        }
        #pragma unroll
        for (int m = 0; m < 4; ++m)
            #pragma unroll
            for (int n = 0; n < 4; ++n) {
                acc[m][n] = __builtin_amdgcn_mfma_f32_16x16x32_bf16(ah[m], bh[n], acc[m][n], 0, 0, 0);
                acc[m][n] = __builtin_amdgcn_mfma_f32_16x16x32_bf16(ah[m], bl[n], acc[m][n], 0, 0, 0);
                acc[m][n] = __builtin_amdgcn_mfma_f32_16x16x32_bf16(al[m], bh[n], acc[m][n], 0, 0, 0);
            }
    }

    // epilogue: per-pixel top-2 over this wave's 64 codes
    float en[4][4];
    #pragma unroll
    for (int m = 0; m < 4; ++m)
        #pragma unroll
        for (int r = 0; r < 4; ++r)
            en[m][r] = wsum[C0 + wc * 64 + m * 16 + (l >> 4) * 4 + r];

    __syncthreads();                       // staging LDS no longer read
    float* bvx = (float*)lds;              // [2 wc][128 px]
    float* svx = bvx + 256;
    int*   bix = (int*)(svx + 256);

    #pragma unroll
    for (int n = 0; n < 4; ++n) {
        float bv = 3.4e38f, sv = 3.4e38f;
        int bi = 0;
        #pragma unroll
        for (int m = 0; m < 4; ++m)
            #pragma unroll
            for (int r = 0; r < 4; ++r) {
                float s = en[m][r] - 2.0f * acc[m][n][r];
                int code = C0 + wc * 64 + m * 16 + (l >> 4) * 4 + r;
                if (s < bv) { sv = bv; bv = s; bi = code; }     // ascending codes in-lane
                else if (s < sv) sv = s;
            }
        #pragma unroll
        for (int x = 16; x <= 32; x <<= 1) {
            float v2 = __shfl_xor(bv, x);
            float s2 = __shfl_xor(sv, x);
            int   i2 = __shfl_xor(bi, x);
            if (v2 < bv || (v2 == bv && i2 < bi)) { sv = fminf(bv, s2); bv = v2; bi = i2; }
            else sv = fminf(sv, v2);
        }
        if ((l >> 4) == 0) {
            int lp = wp * 64 + n * 16 + l;
            bvx[wc * 128 + lp] = bv;
            svx[wc * 128 + lp] = sv;
            bix[wc * 128 + lp] = bi;
        }
    }
    __syncthreads();
    if (t < 128) {                          // merge the two code-halves
        float bv = bvx[t], sv = svx[t];
        int bi = bix[t];
        float v2 = bvx[128 + t], s2 = svx[128 + t];
        int i2 = bix[128 + t];
        if (v2 < bv || (v2 == bv && i2 < bi)) { sv = fminf(bv, s2); bv = v2; bi = i2; }
        else sv = fminf(sv, v2);
        int o = blockIdx.y * NPIX + P0 + t;
        bv8[o] = bv; sv8[o] = sv; bj8[o] = bi;
    }
}

// ---- K1c: combine 8 code-tile triples -> idx + fixup list ------------------
__global__ __launch_bounds__(256) void combine_kernel(const float* __restrict__ bv8,
                                                      const float* __restrict__ sv8,
                                                      const int* __restrict__ bj8,
                                                      float* __restrict__ idxf,
                                                      ushort_t* __restrict__ list,
                                                      int* __restrict__ cnt) {
    int pix = blockIdx.x * 256 + threadIdx.x;
    float bv = bv8[pix], sv = sv8[pix];
    int bi = bj8[pix];
    #pragma unroll
    for (int ct = 1; ct < 8; ++ct) {
        float v2 = bv8[ct * NPIX + pix];
        float s2 = sv8[ct * NPIX + pix];
        int   i2 = bj8[ct * NPIX + pix];
        if (v2 < bv || (v2 == bv && i2 < bi)) { sv = fminf(bv, s2); bv = v2; bi = i2; }
        else sv = fminf(sv, v2);
    }
    idxf[pix] = (float)bi;
    if (sv - bv < GAP_FLAG) {
        int pos = atomicAdd(cnt, 1);
        list[pos] = (ushort_t)pix;
    }
}

// ================== FALLBACK PATH (round-7 argmin), used if ws too small ====
__global__ __launch_bounds__(256) void argmin_kernel(const float* __restrict__ z,
                                                     const float* __restrict__ w,
                                                     const float* __restrict__ enorm,
                                                     float* __restrict__ idxf,
                                                     unsigned long long* __restrict__ flags) {
    __shared__ __align__(16) float smem[64 * 68 + 128 * 68];
    float* zt = smem;
    float* wt = smem + 64 * 68;
    const int t = threadIdx.x;
    const int pr = t & 7;
    const int cr = t >> 3;
    const int P0 = blockIdx.x * 64;
    const int b = P0 >> 12;
    const int hw0 = P0 & (NHW - 1);
    const float* zb = z + (size_t)b * (NC * NHW) + hw0;
    float bestv[8], secv[8];
    int besti[8];
    #pragma unroll
    for (int i = 0; i < 8; ++i) { bestv[i] = 3.4e38f; secv[i] = 3.4e38f; besti[i] = 0; }
    for (int cc = 0; cc < 8; ++cc) {
        float acc[8][4];
        #pragma unroll
        for (int i = 0; i < 8; ++i)
            #pragma unroll
            for (int j = 0; j < 4; ++j) acc[i][j] = 0.0f;
        for (int kc = 0; kc < 4; ++kc) {
            {
                int p = t & 63;
                int k0 = (t >> 6) * 16;
                int f2 = ((p >> 3) & 3) << 2;
                #pragma unroll
                for (int i = 0; i < 16; ++i) {
                    int k = k0 + i;
                    zt[p * 68 + (k ^ f2)] = zb[(size_t)(kc * 64 + k) * NHW + p];
                }
            }
            {
                #pragma unroll
                for (int i = 0; i < 8; ++i) {
                    int f = t + 256 * i;
                    int jj = f >> 4;
                    int k4 = f & 15;
                    float4 v = *(const float4*)&w[(size_t)(cc * 128 + jj) * NC + kc * 64 + k4 * 4];
                    *(float4*)&wt[jj * 68 + k4 * 4] = v;
                }
            }
            __syncthreads();
            #pragma unroll 2
            for (int k = 0; k < 64; k += 4) {
                float4 za[8], wb[4];
                #pragma unroll
                for (int i = 0; i < 8; ++i)
                    za[i] = *(float4*)&zt[(pr + 8 * i) * 68 + (k ^ ((i & 3) << 2))];
                #pragma unroll
                for (int j = 0; j < 4; ++j)
                    wb[j] = *(float4*)&wt[(cr + 32 * j) * 68 + k];
                #pragma unroll
                for (int i = 0; i < 8; ++i)
                    #pragma unroll
                    for (int j = 0; j < 4; ++j)
                        acc[i][j] += za[i].x * wb[j].x + za[i].y * wb[j].y +
                                     za[i].z * wb[j].z + za[i].w * wb[j].w;
            }
            __syncthreads();
        }
        #pragma unroll
        for (int j = 0; j < 4; ++j) {
            int code = cc * 128 + cr + 32 * j;
            float enj = enorm[code];
            #pragma unroll
            for (int i = 0; i < 8; ++i) {
                float s = enj - 2.0f * acc[i][j];
                if (s < bestv[i]) { secv[i] = bestv[i]; bestv[i] = s; besti[i] = code; }
                else if (s < secv[i]) secv[i] = s;
            }
        }
    }
    float* rv = smem;
    int* ri = (int*)(smem + 2048);
    float* rs = smem + 4096;
    #pragma unroll
    for (int i = 0; i < 8; ++i) {
        int p = pr + 8 * i;
        rv[p * 32 + cr] = bestv[i];
        ri[p * 32 + cr] = besti[i];
        rs[p * 32 + cr] = secv[i];
    }
    __syncthreads();
    if (t < 64) {
        int p = t;
        float bv = rv[p * 32], sv = rs[p * 32];
        int bi = ri[p * 32];
        for (int s2 = 1; s2 < 32; ++s2) {
            float v = rv[p * 32 + s2];
            float v2 = rs[p * 32 + s2];
            int ii = ri[p * 32 + s2];
            if (v < bv) { sv = bv; bv = v; bi = ii; }
            else {
                if (v < sv) sv = v;
                if (v == bv && ii < bi) bi = ii;
            }
            if (v2 < sv) sv = v2;
        }
        idxf[P0 + p] = (float)bi;
        unsigned long long mask = __ballot((sv - bv) < GAP_FLAG);
        if (t == 0) flags[blockIdx.x] = mask;
    }
}

__global__ __launch_bounds__(256) void gather_kernel(const unsigned long long* __restrict__ flags,
                                                     ushort_t* __restrict__ list,
                                                     int* __restrict__ cnt) {
    int p = blockIdx.x * 256 + threadIdx.x;
    unsigned long long m = flags[p >> 6];
    if ((m >> (p & 63)) & 1ULL) {
        int pos = atomicAdd(cnt, 1);
        list[pos] = (ushort_t)p;
    }
}
// ================== end fallback ============================================

// ---- K1b: np-fp32-mimic re-argmin, 8 flagged pixels per block --------------
// Same numerics as the passing fixup2: fp64 dot -> single fp32 round;
// d = fl(fl(zs+wsum_j) - 2*mj); argmin with first-index tie-break.
// w float4 loads amortized over 8 pixels (8x less L2 traffic than fixup2).
__global__ __launch_bounds__(256) void fixup3_kernel(const float* __restrict__ z,
                                                     const float* __restrict__ w,
                                                     const float* __restrict__ wsum,
                                                     const ushort_t* __restrict__ list,
                                                     const int* __restrict__ cnt,
                                                     float* __restrict__ idxf) {
    const int count = cnt[0];
    if (count == 0) return;
    const int ngroups = (count + 7) >> 3;
    const int t = threadIdx.x;

    __shared__ __align__(16) char smem_raw[16384 + 8192];
    double (*zd)[NC] = (double(*)[NC])smem_raw;              // 16 KB (dots phase)
    float  (*zf)[NC] = (float(*)[NC])(smem_raw + 16384);     // 8 KB  (zsum phase)
    float* rbv = (float*)(smem_raw + 16384);                 // alias zf (dead)
    int*   rbi = (int*)smem_raw;                             // alias zd (dead)
    __shared__ float zs_sh[8];
    __shared__ int   pix_sh[8];
    __shared__ float r2v[8][32];
    __shared__ int   r2i[8][32];

    for (int g = blockIdx.x; g < ngroups; g += gridDim.x) {
        if (t < 8) {
            int i = g * 8 + t;
            pix_sh[t] = (i < count) ? (int)list[i] : (int)list[0];
        }
        __syncthreads();
        #pragma unroll
        for (int px = 0; px < 8; ++px) {
            int p = pix_sh[px];
            int b = p >> 12, hw = p & (NHW - 1);
            float zv = z[(size_t)b * (NC * NHW) + (size_t)t * NHW + hw];
            zf[px][t] = zv;
            zd[px][t] = (double)zv;
        }
        __syncthreads();
        if (t < 8) zs_sh[t] = np_pair128_sq(zf[t]) + np_pair128_sq(zf[t] + 128);
        __syncthreads();

        float zs_reg[8];
        #pragma unroll
        for (int px = 0; px < 8; ++px) zs_reg[px] = zs_sh[px];

        float bvr[8];
        int   bir[8];
        #pragma unroll
        for (int px = 0; px < 8; ++px) { bvr[px] = 3.4e38f; bir[px] = 0; }

        #pragma unroll
        for (int jo = 0; jo < 2; ++jo) {
            const int j0 = t + jo * 512;           // codes processed ascending:
            const int j1 = j0 + 256;               // t, t+256, t+512, t+768
            const float* wr0 = w + (size_t)j0 * NC;
            const float* wr1 = w + (size_t)j1 * NC;
            double acc0[8], acc1[8];
            #pragma unroll
            for (int px = 0; px < 8; ++px) { acc0[px] = 0.0; acc1[px] = 0.0; }
            for (int k = 0; k < NC; k += 4) {
                float4 wa = *(const float4*)&wr0[k];
                float4 wb = *(const float4*)&wr1[k];
                const float* wap = (const float*)&wa;
                const float* wbp = (const float*)&wb;
                #pragma unroll
                for (int e = 0; e < 4; ++e) {
                    double wea = (double)wap[e];
                    double web = (double)wbp[e];
                    #pragma unroll
                    for (int px = 0; px < 8; ++px) {
                        double zv = zd[px][k + e];
                        acc0[px] += wea * zv;
                        acc1[px] += web * zv;
                    }
                }
            }
            float ws0 = wsum[j0], ws1 = wsum[j1];
            #pragma unroll
            for (int px = 0; px < 8; ++px) {
                float m0 = (float)acc0[px];                  // single round
                float s10 = zs_reg[px] + ws0;                // fl32 add
                float d0 = s10 - 2.0f * m0;                  // single round
                if (d0 < bvr[px] || (d0 == bvr[px] && j0 < bir[px])) { bvr[px] = d0; bir[px] = j0; }
                float m1 = (float)acc1[px];
                float s11 = zs_reg[px] + ws1;
                float d1 = s11 - 2.0f * m1;
                if (d1 < bvr[px] || (d1 == bvr[px] && j1 < bir[px])) { bvr[px] = d1; bir[px] = j1; }
            }
        }
        __syncthreads();                       // zd reads done; alias to rbv/rbi
        #pragma unroll
        for (int px = 0; px < 8; ++px) {
            rbv[px * 256 + t] = bvr[px];
            rbi[px * 256 + t] = bir[px];
        }
        __syncthreads();
        {
            int px = t >> 5, s = t & 31;
            float bv = rbv[px * 256 + s * 8];
            int   bi = rbi[px * 256 + s * 8];
            #pragma unroll
            for (int e = 1; e < 8; ++e) {
                float v2 = rbv[px * 256 + s * 8 + e];
                int   i2 = rbi[px * 256 + s * 8 + e];
                if (v2 < bv || (v2 == bv && i2 < bi)) { bv = v2; bi = i2; }
            }
            r2v[px][s] = bv;
            r2i[px][s] = bi;
        }
        __syncthreads();
        if (t < 8) {
            float bv = r2v[t][0];
            int   bi = r2i[t][0];
            for (int s = 1; s < 32; ++s) {
                float v2 = r2v[t][s];
                int   i2 = r2i[t][s];
                if (v2 < bv || (v2 == bv && i2 < bi)) { bv = v2; bi = i2; }
            }
            if (g * 8 + t < count) idxf[pix_sh[t]] = (float)bi;
        }
        __syncthreads();
    }
}

// ---- K2a: counts histogram -> ncs ------------------------------------------
__global__ __launch_bounds__(1024) void hist_kernel(const float* __restrict__ idxf,
                                                    float* __restrict__ ncs) {
    __shared__ int h[NE];
    int t = threadIdx.x;
    h[t] = 0;
    __syncthreads();
    int gid = blockIdx.x * 1024 + t;
    #pragma unroll
    for (int i = 0; i < 4; ++i) atomicAdd(&h[(int)idxf[gid + i * 16384]], 1);
    __syncthreads();
    if (h[t]) atomicAdd(&ncs[t], (float)h[t]);
}

// ---- K2b: streaming z_q out + loss partials --------------------------------
__global__ __launch_bounds__(256) void out_kernel(const float* __restrict__ z,
                                                  const float* __restrict__ w,
                                                  const float* __restrict__ idxf,
                                                  float* __restrict__ outq,
                                                  float* __restrict__ lpart) {
    const int t = threadIdx.x;
    const int gid = blockIdx.x * 256 + t;
    float lsum = 0.0f;
    #pragma unroll
    for (int ch = 0; ch < 4; ++ch) {
        size_t e0 = ((size_t)gid + (size_t)ch * 262144) * 16;
        int hw0 = (int)(e0 & (NHW - 1));
        int c = (int)((e0 >> 12) & 255);
        int b = (int)(e0 >> 20);
        int pix0 = (b << 12) + hw0;
        #pragma unroll
        for (int q = 0; q < 4; ++q) {
            float4 zv = *(const float4*)&z[e0 + q * 4];
            float4 ov;
            float* po = &ov.x;
            const float* pz = &zv.x;
            #pragma unroll
            for (int k = 0; k < 4; ++k) {
                int id = (int)idxf[pix0 + q * 4 + k];
                float qv = w[(size_t)id * NC + c];
                po[k] = qv;
                float d = qv - pz[k];
                lsum += d * d;
            }
            *(float4*)&outq[e0 + q * 4] = ov;
        }
    }
    #pragma unroll
    for (int off = 32; off > 0; off >>= 1) lsum += __shfl_down(lsum, off);
    __shared__ float ls[4];
    if ((t & 63) == 0) ls[t >> 6] = lsum;
    __syncthreads();
    if (t == 0) lpart[blockIdx.x] = ls[0] + ls[1] + ls[2] + ls[3];
}

// ---- K2c: dw segmented-sum per channel via LDS -----------------------------
__global__ __launch_bounds__(1024) void dwsum_kernel(const float* __restrict__ z,
                                                     const float* __restrict__ idxf,
                                                     const float* __restrict__ ea,
                                                     float* __restrict__ nea) {
    __shared__ float acc[NE];
    const int c = blockIdx.x;
    const int t = threadIdx.x;
    acc[t] = 0.0f;
    __syncthreads();
    const float* zc = z + (size_t)c * NHW;
    #pragma unroll 4
    for (int i = 0; i < 64; ++i) {
        int p = i * 1024 + t;
        int b = p >> 12;
        int hw = p & (NHW - 1);
        float zv = zc[(size_t)b * (NC * NHW) + hw];
        atomicAdd(&acc[(int)idxf[p]], zv);
    }
    __syncthreads();
    size_t o = (size_t)t * NC + c;
    nea[o] = DECAY * ea[o] + (1.0f - DECAY) * acc[t];
}

// ---- K3: finalize ----------------------------------------------------------
__global__ __launch_bounds__(1024) void finalize_kernel(const float* __restrict__ cs,
                                                        const float* __restrict__ lpart,
                                                        float* __restrict__ ncs,
                                                        float* __restrict__ cssm,
                                                        float* __restrict__ loss) {
    int t = threadIdx.x;
    float cnt = ncs[t];
    float v = cs[t] * DECAY + (1.0f - DECAY) * cnt;
    ncs[t] = v;
    __shared__ float red[1024];
    red[t] = v;
    __syncthreads();
    for (int s = 512; s > 0; s >>= 1) {
        if (t < s) red[t] += red[t + s];
        __syncthreads();
    }
    float n = red[0];
    __syncthreads();
    cssm[t] = (v + EPS_) / (n + (float)NE * EPS_) * n;
    red[t] = lpart[t];
    __syncthreads();
    for (int s = 512; s > 0; s >>= 1) {
        if (t < s) red[t] += red[t + s];
        __syncthreads();
    }
    if (t == 0) loss[0] = BETA * red[0] / 16777216.0f;
}

// ---- K4: new_weight --------------------------------------------------------
__global__ __launch_bounds__(256) void newweight_kernel(const float* __restrict__ nea,
                                                        const float* __restrict__ cssm,
                                                        float* __restrict__ nw) {
    int lin = blockIdx.x * 256 + threadIdx.x;
    nw[lin] = nea[lin] / cssm[lin >> 8];
}

extern "C" void kernel_launch(void* const* d_in, const int* in_sizes, int n_in,
                              void* d_out, int out_size, void* d_ws, size_t ws_size,
                              hipStream_t stream) {
    const float* z  = (const float*)d_in[0];
    const float* w  = (const float*)d_in[1];
    const float* cs = (const float*)d_in[2];
    const float* ea = (const float*)d_in[3];

    float* out  = (float*)d_out;
    float* loss = out + OFF_LOSS;
    float* idxf = out + OFF_IDXF;
    float* ncs  = out + OFF_NCS;
    float* nea  = out + OFF_NEA;
    float* nw   = out + OFF_NW;

    float* wsf = (float*)d_ws;
    float* wsum = wsf + WS_WSUM;
    float* cssm = wsf + WS_CSSM;
    float* lpart = wsf + WS_LPART;
    int* cnt = (int*)(wsf + WS_CNT);
    unsigned long long* flags = (unsigned long long*)(wsf + WS_FLAGS);
    ushort_t* list = (ushort_t*)(wsf + WS_LIST);

    hipLaunchKernelGGL(init_kernel, dim3(4), dim3(256), 0, stream, ncs, cnt);
    hipLaunchKernelGGL(wsum_kernel, dim3(16), dim3(64), 0, stream, w, wsum);

    if (ws_size >= (size_t)WS_END * 4) {
        // fast path: bf16-split MFMA GEMM
        ushort_t* whi = (ushort_t*)(wsf + WS_WHI);
        ushort_t* wlo = (ushort_t*)(wsf + WS_WLO);
        ushort_t* zhi = (ushort_t*)(wsf + WS_ZHI);
        ushort_t* zlo = (ushort_t*)(wsf + WS_ZLO);
        float* bv8 = wsf + WS_BV8;
        float* sv8 = wsf + WS_SV8;
        int* bj8 = (int*)(wsf + WS_BJ8);

        hipLaunchKernelGGL(wpack_kernel, dim3(1024), dim3(256), 0, stream, w, whi, wlo);
        hipLaunchKernelGGL(zpack_kernel, dim3(1024, 4), dim3(256), 0, stream, z, zhi, zlo);
        hipLaunchKernelGGL(gemm_kernel, dim3(512, 8), dim3(256), 0, stream,
                           whi, wlo, zhi, zlo, wsum, bv8, sv8, bj8);
        hipLaunchKernelGGL(combine_kernel, dim3(256), dim3(256), 0, stream,
                           bv8, sv8, bj8, idxf, list, cnt);
    } else {
        // fallback: round-7 fp32 VALU argmin
        hipLaunchKernelGGL(argmin_kernel, dim3(1024), dim3(256), 0, stream, z, w, wsum, idxf, flags);
        hipLaunchKernelGGL(gather_kernel, dim3(256), dim3(256), 0, stream, flags, list, cnt);
    }

    hipLaunchKernelGGL(fixup3_kernel, dim3(256), dim3(256), 0, stream, z, w, wsum, list, cnt, idxf);
    hipLaunchKernelGGL(hist_kernel, dim3(16), dim3(1024), 0, stream, idxf, ncs);
    hipLaunchKernelGGL(out_kernel, dim3(1024), dim3(256), 0, stream, z, w, idxf, out, lpart);
    hipLaunchKernelGGL(dwsum_kernel, dim3(256), dim3(1024), 0, stream, z, idxf, ea, nea);
    hipLaunchKernelGGL(finalize_kernel, dim3(1), dim3(1024), 0, stream, cs, lpart, ncs, cssm, loss);
    hipLaunchKernelGGL(newweight_kernel, dim3(1024), dim3(256), 0, stream, nea, cssm, nw);
}

// Round 11
// 378.058 us; speedup vs baseline: 6.4649x; 1.1350x over previous
//
#include <hip/hip_runtime.h>
#include <hip/hip_bf16.h>

typedef unsigned short ushort_t;
typedef __attribute__((ext_vector_type(8))) _Float16 half8;
typedef __attribute__((ext_vector_type(4))) float f32x4;

// Problem constants
#define NB    16
#define NC    256
#define NHW   4096
#define NPIX  65536
#define NE    1024
#define BETA  0.25f
#define DECAY 0.99f
#define EPS_  1e-5f
#define GAP_FLAG 1.25e-4f

// d_out layout (floats)
#define OFF_LOSS 16777216
#define OFF_IDXF 16777217
#define OFF_NCS  16842753
#define OFF_NEA  16843777
#define OFF_NW   17105921

// ws layout (float offsets)
#define WS_WSUM  0
#define WS_CSSM  1024
#define WS_LPART 2048
#define WS_CNT   3072
#define WS_FLAGS 3104
#define WS_LIST  5152
#define WS_WF16  40960                    // 1024*256 fp16 = 131072 float units
#define WS_ZF16  (WS_WF16 + 131072)       // 65536*256 fp16 = 8388608 float units
#define WS_END   (WS_ZF16 + 8388608)

__device__ __forceinline__ float sq_nofma(float x) {
    float s = x * x;
    asm volatile("" : "+v"(s));
    return s;
}

__device__ __forceinline__ float np_pair128_sq(const float* __restrict__ a) {
    float r[8];
    #pragma unroll
    for (int m = 0; m < 8; ++m) r[m] = sq_nofma(a[m]);
    for (int i = 8; i < 128; i += 8) {
        #pragma unroll
        for (int m = 0; m < 8; ++m) r[m] += sq_nofma(a[i + m]);
    }
    return ((r[0] + r[1]) + (r[2] + r[3])) + ((r[4] + r[5]) + (r[6] + r[7]));
}

__device__ __forceinline__ void gload16(const void* g, void* ldsp) {
    __builtin_amdgcn_global_load_lds((const __attribute__((address_space(1))) unsigned int*)g,
                                     (__attribute__((address_space(3))) unsigned int*)ldsp,
                                     16, 0, 0);
}

// ---- K0a: zero counts accumulator + list counter ---------------------------
__global__ __launch_bounds__(256) void init_kernel(float* __restrict__ ncs,
                                                   int* __restrict__ cnt) {
    int gid = blockIdx.x * 256 + threadIdx.x;
    if (gid < NE) ncs[gid] = 0.0f;
    if (gid == 0) cnt[0] = 0;
}

// ---- K0b: wsum[j] = np.float32 pairwise sum of w[j][:]^2 -------------------
__global__ __launch_bounds__(64) void wsum_kernel(const float* __restrict__ w,
                                                  float* __restrict__ wsum) {
    int j = blockIdx.x * 64 + threadIdx.x;
    const float* wr = w + (size_t)j * NC;
    wsum[j] = np_pair128_sq(wr) + np_pair128_sq(wr + 128);
}

// ---- P1: pack w -> fp16, scaled by 1024 (keeps values out of subnormals) ---
__global__ __launch_bounds__(256) void wpack_kernel(const float* __restrict__ w,
                                                    _Float16* __restrict__ wf) {
    int i = blockIdx.x * 256 + threadIdx.x;     // grid 1024 -> 262144
    wf[i] = (_Float16)(w[i] * 1024.0f);
}

// ---- P2: pack z -> fp16 [65536 pix][256 k] (LDS transpose) -----------------
__global__ __launch_bounds__(256) void zpack_kernel(const float* __restrict__ z,
                                                    _Float16* __restrict__ zf) {
    __shared__ float zs[64 * 65];
    const int t = threadIdx.x;
    const int P0 = blockIdx.x * 64;
    const int b = P0 >> 12, hw0 = P0 & (NHW - 1);
    const int K0 = blockIdx.y * 64;
    const int hw = t & 63, cq = t >> 6;
    const float* zb = z + (size_t)b * (NC * NHW) + hw0 + hw;
    #pragma unroll
    for (int i = 0; i < 16; ++i) {
        int kl = cq * 16 + i;
        zs[hw * 65 + kl] = zb[(size_t)(K0 + kl) * NHW];
    }
    __syncthreads();
    const int p = t >> 2, kq = t & 3;
    size_t obase = (size_t)(P0 + p) * NC + K0 + kq * 16;
    #pragma unroll
    for (int h2 = 0; h2 < 2; ++h2) {
        half8 v;
        #pragma unroll
        for (int j2 = 0; j2 < 8; ++j2)
            v[j2] = (_Float16)zs[p * 65 + kq * 16 + h2 * 8 + j2];
        *(half8*)&zf[obase + h2 * 8] = v;
    }
}

// ---- K1: fp16 MFMA distance GEMM, code-tile loop inside, persistent z ------
// score = wsum[code] - 2*dot = wsum - acc * 2^-9 (w was scaled by 1024).
// z tile [128 px][256 k] persistent in LDS (chunk ^= row&7 swizzle);
// w tile [128 codes][32 k] staged per (ct,ks) (chunk ^= (row>>1)&3 swizzle).
__global__ __launch_bounds__(256) void gemm2_kernel(const _Float16* __restrict__ wf,
                                                    const _Float16* __restrict__ zf,
                                                    const float* __restrict__ wsum,
                                                    float* __restrict__ idxf,
                                                    ushort_t* __restrict__ list,
                                                    int* __restrict__ cnt) {
    __shared__ __align__(16) _Float16 zt[128 * 256];   // 64 KB
    __shared__ __align__(16) _Float16 wt[128 * 32];    // 8 KB
    __shared__ float bvx[256], svx[256];
    __shared__ int   bix[256];
    __shared__ float rbv[128], rsv[128];
    __shared__ int   rbi[128];

    const int t = threadIdx.x;
    const int l = t & 63;
    const int w = t >> 6;
    const int P0 = blockIdx.x * 128;
    const int wc = w >> 1, wp = w & 1;

    // persistent z stage: LDS(row,chunk) = global(row, chunk ^ (row&7))
    #pragma unroll
    for (int i = 0; i < 16; ++i) {
        int row = w * 32 + i * 2 + (l >> 5);
        int gc = (l & 31) ^ (row & 7);
        gload16(zf + (size_t)(P0 + row) * NC + gc * 8,
                &zt[w * 8192 + i * 512 + l * 8]);
    }
    if (t < 128) { rbv[t] = 3.4e38f; rsv[t] = 3.4e38f; rbi[t] = 0; }
    __syncthreads();

    for (int ct = 0; ct < 8; ++ct) {
        f32x4 acc[4][4];
        #pragma unroll
        for (int m = 0; m < 4; ++m)
            #pragma unroll
            for (int n = 0; n < 4; ++n)
                #pragma unroll
                for (int e = 0; e < 4; ++e) acc[m][n][e] = 0.0f;

        for (int ks = 0; ks < 8; ++ks) {
            if (ks) __syncthreads();
            #pragma unroll
            for (int i = 0; i < 2; ++i) {
                int row = w * 32 + i * 16 + (l >> 2);
                int gc = (l & 3) ^ ((l >> 3) & 3);   // == (l&3) ^ ((row>>1)&3)
                gload16(wf + (size_t)(ct * 128 + row) * NC + ks * 32 + gc * 8,
                        &wt[w * 1024 + i * 512 + l * 8]);
            }
            __syncthreads();

            half8 a[4], b[4];
            #pragma unroll
            for (int m = 0; m < 4; ++m) {
                int row = wc * 64 + m * 16 + (l & 15);
                int g = (l >> 4) ^ ((row >> 1) & 3);
                a[m] = *(const half8*)&wt[row * 32 + g * 8];
            }
            #pragma unroll
            for (int n = 0; n < 4; ++n) {
                int row = wp * 64 + n * 16 + (l & 15);
                int chunk = (ks * 4 + (l >> 4)) ^ (row & 7);
                b[n] = *(const half8*)&zt[row * 256 + chunk * 8];
            }
            #pragma unroll
            for (int m = 0; m < 4; ++m)
                #pragma unroll
                for (int n = 0; n < 4; ++n)
                    acc[m][n] = __builtin_amdgcn_mfma_f32_16x16x32_f16(a[m], b[n], acc[m][n], 0, 0, 0);
        }

        // epilogue: per-pixel top-2 over this ct's 128 codes
        float en[4][4];
        #pragma unroll
        for (int m = 0; m < 4; ++m)
            #pragma unroll
            for (int r = 0; r < 4; ++r)
                en[m][r] = wsum[ct * 128 + wc * 64 + m * 16 + (l >> 4) * 4 + r];

        #pragma unroll
        for (int n = 0; n < 4; ++n) {
            float bv = 3.4e38f, sv = 3.4e38f;
            int bi = 0;
            #pragma unroll
            for (int m = 0; m < 4; ++m)
                #pragma unroll
                for (int r = 0; r < 4; ++r) {
                    float s = en[m][r] - acc[m][n][r] * 0.001953125f;  // 2^-9
                    int code = ct * 128 + wc * 64 + m * 16 + (l >> 4) * 4 + r;
                    if (s < bv) { sv = bv; bv = s; bi = code; }   // codes ascend in-lane
                    else if (s < sv) sv = s;
                }
            #pragma unroll
            for (int x = 16; x <= 32; x <<= 1) {
                float v2 = __shfl_xor(bv, x);
                float s2 = __shfl_xor(sv, x);
                int   i2 = __shfl_xor(bi, x);
                if (v2 < bv || (v2 == bv && i2 < bi)) { sv = fminf(bv, s2); bv = v2; bi = i2; }
                else sv = fminf(sv, v2);
            }
            if ((l >> 4) == 0) {
                int lp = wp * 64 + n * 16 + l;
                bvx[wc * 128 + lp] = bv;
                svx[wc * 128 + lp] = sv;
                bix[wc * 128 + lp] = bi;
            }
        }
        __syncthreads();
        if (t < 128) {
            float bv = bvx[t], sv = svx[t];
            int bi = bix[t];
            float v2 = bvx[128 + t], s2 = svx[128 + t];
            int i2 = bix[128 + t];
            if (v2 < bv || (v2 == bv && i2 < bi)) { sv = fminf(bv, s2); bv = v2; bi = i2; }
            else sv = fminf(sv, v2);
            // merge into running top-2 (ct ascending -> ties keep lower code)
            if (bv < rbv[t]) { rsv[t] = fminf(rbv[t], sv); rbv[t] = bv; rbi[t] = bi; }
            else rsv[t] = fminf(rsv[t], bv);
        }
        __syncthreads();
    }

    if (t < 128) {
        int pix = P0 + t;
        idxf[pix] = (float)rbi[t];
        if (rsv[t] - rbv[t] < GAP_FLAG) {
            int pos = atomicAdd(cnt, 1);
            list[pos] = (ushort_t)pix;
        }
    }
}

// ================== FALLBACK PATH (round-7 argmin), used if ws too small ====
__global__ __launch_bounds__(256) void argmin_kernel(const float* __restrict__ z,
                                                     const float* __restrict__ w,
                                                     const float* __restrict__ enorm,
                                                     float* __restrict__ idxf,
                                                     unsigned long long* __restrict__ flags) {
    __shared__ __align__(16) float smem[64 * 68 + 128 * 68];
    float* zt = smem;
    float* wt = smem + 64 * 68;
    const int t = threadIdx.x;
    const int pr = t & 7;
    const int cr = t >> 3;
    const int P0 = blockIdx.x * 64;
    const int b = P0 >> 12;
    const int hw0 = P0 & (NHW - 1);
    const float* zb = z + (size_t)b * (NC * NHW) + hw0;
    float bestv[8], secv[8];
    int besti[8];
    #pragma unroll
    for (int i = 0; i < 8; ++i) { bestv[i] = 3.4e38f; secv[i] = 3.4e38f; besti[i] = 0; }
    for (int cc = 0; cc < 8; ++cc) {
        float acc[8][4];
        #pragma unroll
        for (int i = 0; i < 8; ++i)
            #pragma unroll
            for (int j = 0; j < 4; ++j) acc[i][j] = 0.0f;
        for (int kc = 0; kc < 4; ++kc) {
            {
                int p = t & 63;
                int k0 = (t >> 6) * 16;
                int f2 = ((p >> 3) & 3) << 2;
                #pragma unroll
                for (int i = 0; i < 16; ++i) {
                    int k = k0 + i;
                    zt[p * 68 + (k ^ f2)] = zb[(size_t)(kc * 64 + k) * NHW + p];
                }
            }
            {
                #pragma unroll
                for (int i = 0; i < 8; ++i) {
                    int f = t + 256 * i;
                    int jj = f >> 4;
                    int k4 = f & 15;
                    float4 v = *(const float4*)&w[(size_t)(cc * 128 + jj) * NC + kc * 64 + k4 * 4];
                    *(float4*)&wt[jj * 68 + k4 * 4] = v;
                }
            }
            __syncthreads();
            #pragma unroll 2
            for (int k = 0; k < 64; k += 4) {
                float4 za[8], wb[4];
                #pragma unroll
                for (int i = 0; i < 8; ++i)
                    za[i] = *(float4*)&zt[(pr + 8 * i) * 68 + (k ^ ((i & 3) << 2))];
                #pragma unroll
                for (int j = 0; j < 4; ++j)
                    wb[j] = *(float4*)&wt[(cr + 32 * j) * 68 + k];
                #pragma unroll
                for (int i = 0; i < 8; ++i)
                    #pragma unroll
                    for (int j = 0; j < 4; ++j)
                        acc[i][j] += za[i].x * wb[j].x + za[i].y * wb[j].y +
                                     za[i].z * wb[j].z + za[i].w * wb[j].w;
            }
            __syncthreads();
        }
        #pragma unroll
        for (int j = 0; j < 4; ++j) {
            int code = cc * 128 + cr + 32 * j;
            float enj = enorm[code];
            #pragma unroll
            for (int i = 0; i < 8; ++i) {
                float s = enj - 2.0f * acc[i][j];
                if (s < bestv[i]) { secv[i] = bestv[i]; bestv[i] = s; besti[i] = code; }
                else if (s < secv[i]) secv[i] = s;
            }
        }
    }
    float* rv = smem;
    int* ri = (int*)(smem + 2048);
    float* rs = smem + 4096;
    #pragma unroll
    for (int i = 0; i < 8; ++i) {
        int p = pr + 8 * i;
        rv[p * 32 + cr] = bestv[i];
        ri[p * 32 + cr] = besti[i];
        rs[p * 32 + cr] = secv[i];
    }
    __syncthreads();
    if (t < 64) {
        int p = t;
        float bv = rv[p * 32], sv = rs[p * 32];
        int bi = ri[p * 32];
        for (int s2 = 1; s2 < 32; ++s2) {
            float v = rv[p * 32 + s2];
            float v2 = rs[p * 32 + s2];
            int ii = ri[p * 32 + s2];
            if (v < bv) { sv = bv; bv = v; bi = ii; }
            else {
                if (v < sv) sv = v;
                if (v == bv && ii < bi) bi = ii;
            }
            if (v2 < sv) sv = v2;
        }
        idxf[P0 + p] = (float)bi;
        unsigned long long mask = __ballot((sv - bv) < GAP_FLAG);
        if (t == 0) flags[blockIdx.x] = mask;
    }
}

__global__ __launch_bounds__(256) void gather_kernel(const unsigned long long* __restrict__ flags,
                                                     ushort_t* __restrict__ list,
                                                     int* __restrict__ cnt) {
    int p = blockIdx.x * 256 + threadIdx.x;
    unsigned long long m = flags[p >> 6];
    if ((m >> (p & 63)) & 1ULL) {
        int pos = atomicAdd(cnt, 1);
        list[pos] = (ushort_t)p;
    }
}
// ================== end fallback ============================================

// ---- K1b: np-fp32-mimic re-argmin, 8 flagged pixels per block --------------
__global__ __launch_bounds__(256) void fixup3_kernel(const float* __restrict__ z,
                                                     const float* __restrict__ w,
                                                     const float* __restrict__ wsum,
                                                     const ushort_t* __restrict__ list,
                                                     const int* __restrict__ cnt,
                                                     float* __restrict__ idxf) {
    const int count = cnt[0];
    if (count == 0) return;
    const int ngroups = (count + 7) >> 3;
    const int t = threadIdx.x;

    __shared__ __align__(16) char smem_raw[16384 + 8192];
    double (*zd)[NC] = (double(*)[NC])smem_raw;
    float  (*zf)[NC] = (float(*)[NC])(smem_raw + 16384);
    float* rbv = (float*)(smem_raw + 16384);
    int*   rbi = (int*)smem_raw;
    __shared__ float zs_sh[8];
    __shared__ int   pix_sh[8];
    __shared__ float r2v[8][32];
    __shared__ int   r2i[8][32];

    for (int g = blockIdx.x; g < ngroups; g += gridDim.x) {
        if (t < 8) {
            int i = g * 8 + t;
            pix_sh[t] = (i < count) ? (int)list[i] : (int)list[0];
        }
        __syncthreads();
        #pragma unroll
        for (int px = 0; px < 8; ++px) {
            int p = pix_sh[px];
            int b = p >> 12, hw = p & (NHW - 1);
            float zv = z[(size_t)b * (NC * NHW) + (size_t)t * NHW + hw];
            zf[px][t] = zv;
            zd[px][t] = (double)zv;
        }
        __syncthreads();
        if (t < 8) zs_sh[t] = np_pair128_sq(zf[t]) + np_pair128_sq(zf[t] + 128);
        __syncthreads();

        float zs_reg[8];
        #pragma unroll
        for (int px = 0; px < 8; ++px) zs_reg[px] = zs_sh[px];

        float bvr[8];
        int   bir[8];
        #pragma unroll
        for (int px = 0; px < 8; ++px) { bvr[px] = 3.4e38f; bir[px] = 0; }

        #pragma unroll
        for (int jo = 0; jo < 2; ++jo) {
            const int j0 = t + jo * 512;
            const int j1 = j0 + 256;
            const float* wr0 = w + (size_t)j0 * NC;
            const float* wr1 = w + (size_t)j1 * NC;
            double acc0[8], acc1[8];
            #pragma unroll
            for (int px = 0; px < 8; ++px) { acc0[px] = 0.0; acc1[px] = 0.0; }
            for (int k = 0; k < NC; k += 4) {
                float4 wa = *(const float4*)&wr0[k];
                float4 wb = *(const float4*)&wr1[k];
                const float* wap = (const float*)&wa;
                const float* wbp = (const float*)&wb;
                #pragma unroll
                for (int e = 0; e < 4; ++e) {
                    double wea = (double)wap[e];
                    double web = (double)wbp[e];
                    #pragma unroll
                    for (int px = 0; px < 8; ++px) {
                        double zv = zd[px][k + e];
                        acc0[px] += wea * zv;
                        acc1[px] += web * zv;
                    }
                }
            }
            float ws0 = wsum[j0], ws1 = wsum[j1];
            #pragma unroll
            for (int px = 0; px < 8; ++px) {
                float m0 = (float)acc0[px];
                float s10 = zs_reg[px] + ws0;
                float d0 = s10 - 2.0f * m0;
                if (d0 < bvr[px] || (d0 == bvr[px] && j0 < bir[px])) { bvr[px] = d0; bir[px] = j0; }
                float m1 = (float)acc1[px];
                float s11 = zs_reg[px] + ws1;
                float d1 = s11 - 2.0f * m1;
                if (d1 < bvr[px] || (d1 == bvr[px] && j1 < bir[px])) { bvr[px] = d1; bir[px] = j1; }
            }
        }
        __syncthreads();
        #pragma unroll
        for (int px = 0; px < 8; ++px) {
            rbv[px * 256 + t] = bvr[px];
            rbi[px * 256 + t] = bir[px];
        }
        __syncthreads();
        {
            int px = t >> 5, s = t & 31;
            float bv = rbv[px * 256 + s * 8];
            int   bi = rbi[px * 256 + s * 8];
            #pragma unroll
            for (int e = 1; e < 8; ++e) {
                float v2 = rbv[px * 256 + s * 8 + e];
                int   i2 = rbi[px * 256 + s * 8 + e];
                if (v2 < bv || (v2 == bv && i2 < bi)) { bv = v2; bi = i2; }
            }
            r2v[px][s] = bv;
            r2i[px][s] = bi;
        }
        __syncthreads();
        if (t < 8) {
            float bv = r2v[t][0];
            int   bi = r2i[t][0];
            for (int s = 1; s < 32; ++s) {
                float v2 = r2v[t][s];
                int   i2 = r2i[t][s];
                if (v2 < bv || (v2 == bv && i2 < bi)) { bv = v2; bi = i2; }
            }
            if (g * 8 + t < count) idxf[pix_sh[t]] = (float)bi;
        }
        __syncthreads();
    }
}

// ---- K2a: counts histogram -> ncs ------------------------------------------
__global__ __launch_bounds__(1024) void hist_kernel(const float* __restrict__ idxf,
                                                    float* __restrict__ ncs) {
    __shared__ int h[NE];
    int t = threadIdx.x;
    h[t] = 0;
    __syncthreads();
    int gid = blockIdx.x * 1024 + t;
    #pragma unroll
    for (int i = 0; i < 4; ++i) atomicAdd(&h[(int)idxf[gid + i * 16384]], 1);
    __syncthreads();
    if (h[t]) atomicAdd(&ncs[t], (float)h[t]);
}

// ---- K2b: streaming z_q out + loss partials --------------------------------
__global__ __launch_bounds__(256) void out_kernel(const float* __restrict__ z,
                                                  const float* __restrict__ w,
                                                  const float* __restrict__ idxf,
                                                  float* __restrict__ outq,
                                                  float* __restrict__ lpart) {
    const int t = threadIdx.x;
    const int gid = blockIdx.x * 256 + t;
    float lsum = 0.0f;
    #pragma unroll
    for (int ch = 0; ch < 4; ++ch) {
        size_t e0 = ((size_t)gid + (size_t)ch * 262144) * 16;
        int hw0 = (int)(e0 & (NHW - 1));
        int c = (int)((e0 >> 12) & 255);
        int b = (int)(e0 >> 20);
        int pix0 = (b << 12) + hw0;
        #pragma unroll
        for (int q = 0; q < 4; ++q) {
            float4 zv = *(const float4*)&z[e0 + q * 4];
            float4 ov;
            float* po = &ov.x;
            const float* pz = &zv.x;
            #pragma unroll
            for (int k = 0; k < 4; ++k) {
                int id = (int)idxf[pix0 + q * 4 + k];
                float qv = w[(size_t)id * NC + c];
                po[k] = qv;
                float d = qv - pz[k];
                lsum += d * d;
            }
            *(float4*)&outq[e0 + q * 4] = ov;
        }
    }
    #pragma unroll
    for (int off = 32; off > 0; off >>= 1) lsum += __shfl_down(lsum, off);
    __shared__ float ls[4];
    if ((t & 63) == 0) ls[t >> 6] = lsum;
    __syncthreads();
    if (t == 0) lpart[blockIdx.x] = ls[0] + ls[1] + ls[2] + ls[3];
}

// ---- K2c: dw segmented-sum per channel via LDS -----------------------------
__global__ __launch_bounds__(1024) void dwsum_kernel(const float* __restrict__ z,
                                                     const float* __restrict__ idxf,
                                                     const float* __restrict__ ea,
                                                     float* __restrict__ nea) {
    __shared__ float acc[NE];
    const int c = blockIdx.x;
    const int t = threadIdx.x;
    acc[t] = 0.0f;
    __syncthreads();
    const float* zc = z + (size_t)c * NHW;
    #pragma unroll 4
    for (int i = 0; i < 64; ++i) {
        int p = i * 1024 + t;
        int b = p >> 12;
        int hw = p & (NHW - 1);
        float zv = zc[(size_t)b * (NC * NHW) + hw];
        atomicAdd(&acc[(int)idxf[p]], zv);
    }
    __syncthreads();
    size_t o = (size_t)t * NC + c;
    nea[o] = DECAY * ea[o] + (1.0f - DECAY) * acc[t];
}

// ---- K3: finalize ----------------------------------------------------------
__global__ __launch_bounds__(1024) void finalize_kernel(const float* __restrict__ cs,
                                                        const float* __restrict__ lpart,
                                                        float* __restrict__ ncs,
                                                        float* __restrict__ cssm,
                                                        float* __restrict__ loss) {
    int t = threadIdx.x;
    float cnt = ncs[t];
    float v = cs[t] * DECAY + (1.0f - DECAY) * cnt;
    ncs[t] = v;
    __shared__ float red[1024];
    red[t] = v;
    __syncthreads();
    for (int s = 512; s > 0; s >>= 1) {
        if (t < s) red[t] += red[t + s];
        __syncthreads();
    }
    float n = red[0];
    __syncthreads();
    cssm[t] = (v + EPS_) / (n + (float)NE * EPS_) * n;
    red[t] = lpart[t];
    __syncthreads();
    for (int s = 512; s > 0; s >>= 1) {
        if (t < s) red[t] += red[t + s];
        __syncthreads();
    }
    if (t == 0) loss[0] = BETA * red[0] / 16777216.0f;
}

// ---- K4: new_weight --------------------------------------------------------
__global__ __launch_bounds__(256) void newweight_kernel(const float* __restrict__ nea,
                                                        const float* __restrict__ cssm,
                                                        float* __restrict__ nw) {
    int lin = blockIdx.x * 256 + threadIdx.x;
    nw[lin] = nea[lin] / cssm[lin >> 8];
}

extern "C" void kernel_launch(void* const* d_in, const int* in_sizes, int n_in,
                              void* d_out, int out_size, void* d_ws, size_t ws_size,
                              hipStream_t stream) {
    const float* z  = (const float*)d_in[0];
    const float* w  = (const float*)d_in[1];
    const float* cs = (const float*)d_in[2];
    const float* ea = (const float*)d_in[3];

    float* out  = (float*)d_out;
    float* loss = out + OFF_LOSS;
    float* idxf = out + OFF_IDXF;
    float* ncs  = out + OFF_NCS;
    float* nea  = out + OFF_NEA;
    float* nw   = out + OFF_NW;

    float* wsf = (float*)d_ws;
    float* wsum = wsf + WS_WSUM;
    float* cssm = wsf + WS_CSSM;
    float* lpart = wsf + WS_LPART;
    int* cnt = (int*)(wsf + WS_CNT);
    unsigned long long* flags = (unsigned long long*)(wsf + WS_FLAGS);
    ushort_t* list = (ushort_t*)(wsf + WS_LIST);

    hipLaunchKernelGGL(init_kernel, dim3(4), dim3(256), 0, stream, ncs, cnt);
    hipLaunchKernelGGL(wsum_kernel, dim3(16), dim3(64), 0, stream, w, wsum);

    if (ws_size >= (size_t)WS_END * 4) {
        _Float16* wf16 = (_Float16*)(wsf + WS_WF16);
        _Float16* zf16 = (_Float16*)(wsf + WS_ZF16);
        hipLaunchKernelGGL(wpack_kernel, dim3(1024), dim3(256), 0, stream, w, wf16);
        hipLaunchKernelGGL(zpack_kernel, dim3(1024, 4), dim3(256), 0, stream, z, zf16);
        hipLaunchKernelGGL(gemm2_kernel, dim3(512), dim3(256), 0, stream,
                           wf16, zf16, wsum, idxf, list, cnt);
    } else {
        hipLaunchKernelGGL(argmin_kernel, dim3(1024), dim3(256), 0, stream, z, w, wsum, idxf, flags);
        hipLaunchKernelGGL(gather_kernel, dim3(256), dim3(256), 0, stream, flags, list, cnt);
    }

    hipLaunchKernelGGL(fixup3_kernel, dim3(256), dim3(256), 0, stream, z, w, wsum, list, cnt, idxf);
    hipLaunchKernelGGL(hist_kernel, dim3(16), dim3(1024), 0, stream, idxf, ncs);
    hipLaunchKernelGGL(out_kernel, dim3(1024), dim3(256), 0, stream, z, w, idxf, out, lpart);
    hipLaunchKernelGGL(dwsum_kernel, dim3(256), dim3(1024), 0, stream, z, idxf, ea, nea);
    hipLaunchKernelGGL(finalize_kernel, dim3(1), dim3(1024), 0, stream, cs, lpart, ncs, cssm, loss);
    hipLaunchKernelGGL(newweight_kernel, dim3(1024), dim3(256), 0, stream, nea, cssm, nw);
}

// Round 12
// 299.193 us; speedup vs baseline: 8.1690x; 1.2636x over previous
//
#include <hip/hip_runtime.h>
#include <hip/hip_bf16.h>

typedef unsigned short ushort_t;
typedef __attribute__((ext_vector_type(8))) _Float16 half8;
typedef __attribute__((ext_vector_type(4))) float f32x4;

// Problem constants
#define NB    16
#define NC    256
#define NHW   4096
#define NPIX  65536
#define NE    1024
#define BETA  0.25f
#define DECAY 0.99f
#define EPS_  1e-5f
#define GAP_FLAG 1.25e-4f

// d_out layout (floats)
#define OFF_LOSS 16777216
#define OFF_IDXF 16777217
#define OFF_NCS  16842753
#define OFF_NEA  16843777
#define OFF_NW   17105921

// ws layout (float offsets)
#define WS_WSUM  0
#define WS_CSSM  1024
#define WS_LPART 2048
#define WS_CNT   3072
#define WS_FLAGS 3104
#define WS_LIST  5152
#define WS_WF16  40960                    // 1024*256 fp16 = 131072 float units
#define WS_ZF16  (WS_WF16 + 131072)       // 65536*256 fp16 = 8388608 float units
#define WS_END   (WS_ZF16 + 8388608)

__device__ __forceinline__ float sq_nofma(float x) {
    float s = x * x;
    asm volatile("" : "+v"(s));
    return s;
}

__device__ __forceinline__ float np_pair128_sq(const float* __restrict__ a) {
    float r[8];
    #pragma unroll
    for (int m = 0; m < 8; ++m) r[m] = sq_nofma(a[m]);
    for (int i = 8; i < 128; i += 8) {
        #pragma unroll
        for (int m = 0; m < 8; ++m) r[m] += sq_nofma(a[i + m]);
    }
    return ((r[0] + r[1]) + (r[2] + r[3])) + ((r[4] + r[5]) + (r[6] + r[7]));
}

__device__ __forceinline__ void gload16(const void* g, void* ldsp) {
    __builtin_amdgcn_global_load_lds((const __attribute__((address_space(1))) unsigned int*)g,
                                     (__attribute__((address_space(3))) unsigned int*)ldsp,
                                     16, 0, 0);
}

// ---- K0a: zero counts accumulator + list counter ---------------------------
__global__ __launch_bounds__(256) void init_kernel(float* __restrict__ ncs,
                                                   int* __restrict__ cnt) {
    int gid = blockIdx.x * 256 + threadIdx.x;
    if (gid < NE) ncs[gid] = 0.0f;
    if (gid == 0) cnt[0] = 0;
}

// ---- K0b: wsum[j] = np.float32 pairwise sum of w[j][:]^2 -------------------
__global__ __launch_bounds__(64) void wsum_kernel(const float* __restrict__ w,
                                                  float* __restrict__ wsum) {
    int j = blockIdx.x * 64 + threadIdx.x;
    const float* wr = w + (size_t)j * NC;
    wsum[j] = np_pair128_sq(wr) + np_pair128_sq(wr + 128);
}

// ---- P1: pack w -> fp16, scaled by 1024 (keeps values out of subnormals) ---
__global__ __launch_bounds__(256) void wpack_kernel(const float* __restrict__ w,
                                                    _Float16* __restrict__ wf) {
    int i = blockIdx.x * 256 + threadIdx.x;     // grid 1024 -> 262144
    wf[i] = (_Float16)(w[i] * 1024.0f);
}

// ---- P2: pack z -> fp16 [65536 pix][256 k] (LDS transpose) -----------------
__global__ __launch_bounds__(256) void zpack_kernel(const float* __restrict__ z,
                                                    _Float16* __restrict__ zf) {
    __shared__ float zs[64 * 65];
    const int t = threadIdx.x;
    const int P0 = blockIdx.x * 64;
    const int b = P0 >> 12, hw0 = P0 & (NHW - 1);
    const int K0 = blockIdx.y * 64;
    const int hw = t & 63, cq = t >> 6;
    const float* zb = z + (size_t)b * (NC * NHW) + hw0 + hw;
    #pragma unroll
    for (int i = 0; i < 16; ++i) {
        int kl = cq * 16 + i;
        zs[hw * 65 + kl] = zb[(size_t)(K0 + kl) * NHW];
    }
    __syncthreads();
    const int p = t >> 2, kq = t & 3;
    size_t obase = (size_t)(P0 + p) * NC + K0 + kq * 16;
    #pragma unroll
    for (int h2 = 0; h2 < 2; ++h2) {
        half8 v;
        #pragma unroll
        for (int j2 = 0; j2 < 8; ++j2)
            v[j2] = (_Float16)zs[p * 65 + kq * 16 + h2 * 8 + j2];
        *(half8*)&zf[obase + h2 * 8] = v;
    }
}

// ---- K1: fp16 MFMA distance GEMM, code-tile loop inside, persistent z ------
__global__ __launch_bounds__(256) void gemm2_kernel(const _Float16* __restrict__ wf,
                                                    const _Float16* __restrict__ zf,
                                                    const float* __restrict__ wsum,
                                                    float* __restrict__ idxf,
                                                    ushort_t* __restrict__ list,
                                                    int* __restrict__ cnt) {
    __shared__ __align__(16) _Float16 zt[128 * 256];   // 64 KB
    __shared__ __align__(16) _Float16 wt[128 * 32];    // 8 KB
    __shared__ float bvx[256], svx[256];
    __shared__ int   bix[256];
    __shared__ float rbv[128], rsv[128];
    __shared__ int   rbi[128];

    const int t = threadIdx.x;
    const int l = t & 63;
    const int w = t >> 6;
    const int P0 = blockIdx.x * 128;
    const int wc = w >> 1, wp = w & 1;

    // persistent z stage: LDS(row,chunk) = global(row, chunk ^ (row&7))
    #pragma unroll
    for (int i = 0; i < 16; ++i) {
        int row = w * 32 + i * 2 + (l >> 5);
        int gc = (l & 31) ^ (row & 7);
        gload16(zf + (size_t)(P0 + row) * NC + gc * 8,
                &zt[w * 8192 + i * 512 + l * 8]);
    }
    if (t < 128) { rbv[t] = 3.4e38f; rsv[t] = 3.4e38f; rbi[t] = 0; }
    __syncthreads();

    for (int ct = 0; ct < 8; ++ct) {
        f32x4 acc[4][4];
        #pragma unroll
        for (int m = 0; m < 4; ++m)
            #pragma unroll
            for (int n = 0; n < 4; ++n)
                #pragma unroll
                for (int e = 0; e < 4; ++e) acc[m][n][e] = 0.0f;

        for (int ks = 0; ks < 8; ++ks) {
            if (ks) __syncthreads();
            #pragma unroll
            for (int i = 0; i < 2; ++i) {
                int row = w * 32 + i * 16 + (l >> 2);
                int gc = (l & 3) ^ ((l >> 3) & 3);   // == (l&3) ^ ((row>>1)&3)
                gload16(wf + (size_t)(ct * 128 + row) * NC + ks * 32 + gc * 8,
                        &wt[w * 1024 + i * 512 + l * 8]);
            }
            __syncthreads();

            half8 a[4], b[4];
            #pragma unroll
            for (int m = 0; m < 4; ++m) {
                int row = wc * 64 + m * 16 + (l & 15);
                int g = (l >> 4) ^ ((row >> 1) & 3);
                a[m] = *(const half8*)&wt[row * 32 + g * 8];
            }
            #pragma unroll
            for (int n = 0; n < 4; ++n) {
                int row = wp * 64 + n * 16 + (l & 15);
                int chunk = (ks * 4 + (l >> 4)) ^ (row & 7);
                b[n] = *(const half8*)&zt[row * 256 + chunk * 8];
            }
            #pragma unroll
            for (int m = 0; m < 4; ++m)
                #pragma unroll
                for (int n = 0; n < 4; ++n)
                    acc[m][n] = __builtin_amdgcn_mfma_f32_16x16x32_f16(a[m], b[n], acc[m][n], 0, 0, 0);
        }

        // epilogue: per-pixel top-2 over this ct's 128 codes
        float en[4][4];
        #pragma unroll
        for (int m = 0; m < 4; ++m)
            #pragma unroll
            for (int r = 0; r < 4; ++r)
                en[m][r] = wsum[ct * 128 + wc * 64 + m * 16 + (l >> 4) * 4 + r];

        #pragma unroll
        for (int n = 0; n < 4; ++n) {
            float bv = 3.4e38f, sv = 3.4e38f;
            int bi = 0;
            #pragma unroll
            for (int m = 0; m < 4; ++m)
                #pragma unroll
                for (int r = 0; r < 4; ++r) {
                    float s = en[m][r] - acc[m][n][r] * 0.001953125f;  // 2^-9
                    int code = ct * 128 + wc * 64 + m * 16 + (l >> 4) * 4 + r;
                    if (s < bv) { sv = bv; bv = s; bi = code; }   // codes ascend in-lane
                    else if (s < sv) sv = s;
                }
            #pragma unroll
            for (int x = 16; x <= 32; x <<= 1) {
                float v2 = __shfl_xor(bv, x);
                float s2 = __shfl_xor(sv, x);
                int   i2 = __shfl_xor(bi, x);
                if (v2 < bv || (v2 == bv && i2 < bi)) { sv = fminf(bv, s2); bv = v2; bi = i2; }
                else sv = fminf(sv, v2);
            }
            if ((l >> 4) == 0) {
                int lp = wp * 64 + n * 16 + l;
                bvx[wc * 128 + lp] = bv;
                svx[wc * 128 + lp] = sv;
                bix[wc * 128 + lp] = bi;
            }
        }
        __syncthreads();
        if (t < 128) {
            float bv = bvx[t], sv = svx[t];
            int bi = bix[t];
            float v2 = bvx[128 + t], s2 = svx[128 + t];
            int i2 = bix[128 + t];
            if (v2 < bv || (v2 == bv && i2 < bi)) { sv = fminf(bv, s2); bv = v2; bi = i2; }
            else sv = fminf(sv, v2);
            if (bv < rbv[t]) { rsv[t] = fminf(rbv[t], sv); rbv[t] = bv; rbi[t] = bi; }
            else rsv[t] = fminf(rsv[t], bv);
        }
        __syncthreads();
    }

    if (t < 128) {
        int pix = P0 + t;
        idxf[pix] = (float)rbi[t];
        if (rsv[t] - rbv[t] < GAP_FLAG) {
            int pos = atomicAdd(cnt, 1);
            list[pos] = (ushort_t)pix;
        }
    }
}

// ================== FALLBACK PATH (round-7 argmin), used if ws too small ====
__global__ __launch_bounds__(256) void argmin_kernel(const float* __restrict__ z,
                                                     const float* __restrict__ w,
                                                     const float* __restrict__ enorm,
                                                     float* __restrict__ idxf,
                                                     unsigned long long* __restrict__ flags) {
    __shared__ __align__(16) float smem[64 * 68 + 128 * 68];
    float* zt = smem;
    float* wt = smem + 64 * 68;
    const int t = threadIdx.x;
    const int pr = t & 7;
    const int cr = t >> 3;
    const int P0 = blockIdx.x * 64;
    const int b = P0 >> 12;
    const int hw0 = P0 & (NHW - 1);
    const float* zb = z + (size_t)b * (NC * NHW) + hw0;
    float bestv[8], secv[8];
    int besti[8];
    #pragma unroll
    for (int i = 0; i < 8; ++i) { bestv[i] = 3.4e38f; secv[i] = 3.4e38f; besti[i] = 0; }
    for (int cc = 0; cc < 8; ++cc) {
        float acc[8][4];
        #pragma unroll
        for (int i = 0; i < 8; ++i)
            #pragma unroll
            for (int j = 0; j < 4; ++j) acc[i][j] = 0.0f;
        for (int kc = 0; kc < 4; ++kc) {
            {
                int p = t & 63;
                int k0 = (t >> 6) * 16;
                int f2 = ((p >> 3) & 3) << 2;
                #pragma unroll
                for (int i = 0; i < 16; ++i) {
                    int k = k0 + i;
                    zt[p * 68 + (k ^ f2)] = zb[(size_t)(kc * 64 + k) * NHW + p];
                }
            }
            {
                #pragma unroll
                for (int i = 0; i < 8; ++i) {
                    int f = t + 256 * i;
                    int jj = f >> 4;
                    int k4 = f & 15;
                    float4 v = *(const float4*)&w[(size_t)(cc * 128 + jj) * NC + kc * 64 + k4 * 4];
                    *(float4*)&wt[jj * 68 + k4 * 4] = v;
                }
            }
            __syncthreads();
            #pragma unroll 2
            for (int k = 0; k < 64; k += 4) {
                float4 za[8], wb[4];
                #pragma unroll
                for (int i = 0; i < 8; ++i)
                    za[i] = *(float4*)&zt[(pr + 8 * i) * 68 + (k ^ ((i & 3) << 2))];
                #pragma unroll
                for (int j = 0; j < 4; ++j)
                    wb[j] = *(float4*)&wt[(cr + 32 * j) * 68 + k];
                #pragma unroll
                for (int i = 0; i < 8; ++i)
                    #pragma unroll
                    for (int j = 0; j < 4; ++j)
                        acc[i][j] += za[i].x * wb[j].x + za[i].y * wb[j].y +
                                     za[i].z * wb[j].z + za[i].w * wb[j].w;
            }
            __syncthreads();
        }
        #pragma unroll
        for (int j = 0; j < 4; ++j) {
            int code = cc * 128 + cr + 32 * j;
            float enj = enorm[code];
            #pragma unroll
            for (int i = 0; i < 8; ++i) {
                float s = enj - 2.0f * acc[i][j];
                if (s < bestv[i]) { secv[i] = bestv[i]; bestv[i] = s; besti[i] = code; }
                else if (s < secv[i]) secv[i] = s;
            }
        }
    }
    float* rv = smem;
    int* ri = (int*)(smem + 2048);
    float* rs = smem + 4096;
    #pragma unroll
    for (int i = 0; i < 8; ++i) {
        int p = pr + 8 * i;
        rv[p * 32 + cr] = bestv[i];
        ri[p * 32 + cr] = besti[i];
        rs[p * 32 + cr] = secv[i];
    }
    __syncthreads();
    if (t < 64) {
        int p = t;
        float bv = rv[p * 32], sv = rs[p * 32];
        int bi = ri[p * 32];
        for (int s2 = 1; s2 < 32; ++s2) {
            float v = rv[p * 32 + s2];
            float v2 = rs[p * 32 + s2];
            int ii = ri[p * 32 + s2];
            if (v < bv) { sv = bv; bv = v; bi = ii; }
            else {
                if (v < sv) sv = v;
                if (v == bv && ii < bi) bi = ii;
            }
            if (v2 < sv) sv = v2;
        }
        idxf[P0 + p] = (float)bi;
        unsigned long long mask = __ballot((sv - bv) < GAP_FLAG);
        if (t == 0) flags[blockIdx.x] = mask;
    }
}

__global__ __launch_bounds__(256) void gather_kernel(const unsigned long long* __restrict__ flags,
                                                     ushort_t* __restrict__ list,
                                                     int* __restrict__ cnt) {
    int p = blockIdx.x * 256 + threadIdx.x;
    unsigned long long m = flags[p >> 6];
    if ((m >> (p & 63)) & 1ULL) {
        int pos = atomicAdd(cnt, 1);
        list[pos] = (ushort_t)p;
    }
}
// ================== end fallback ============================================

// ---- K1b: np-fp32-mimic re-argmin, 8 flagged pixels per block --------------
__global__ __launch_bounds__(256) void fixup3_kernel(const float* __restrict__ z,
                                                     const float* __restrict__ w,
                                                     const float* __restrict__ wsum,
                                                     const ushort_t* __restrict__ list,
                                                     const int* __restrict__ cnt,
                                                     float* __restrict__ idxf) {
    const int count = cnt[0];
    if (count == 0) return;
    const int ngroups = (count + 7) >> 3;
    const int t = threadIdx.x;

    __shared__ __align__(16) char smem_raw[16384 + 8192];
    double (*zd)[NC] = (double(*)[NC])smem_raw;
    float  (*zf)[NC] = (float(*)[NC])(smem_raw + 16384);
    float* rbv = (float*)(smem_raw + 16384);
    int*   rbi = (int*)smem_raw;
    __shared__ float zs_sh[8];
    __shared__ int   pix_sh[8];
    __shared__ float r2v[8][32];
    __shared__ int   r2i[8][32];

    for (int g = blockIdx.x; g < ngroups; g += gridDim.x) {
        if (t < 8) {
            int i = g * 8 + t;
            pix_sh[t] = (i < count) ? (int)list[i] : (int)list[0];
        }
        __syncthreads();
        #pragma unroll
        for (int px = 0; px < 8; ++px) {
            int p = pix_sh[px];
            int b = p >> 12, hw = p & (NHW - 1);
            float zv = z[(size_t)b * (NC * NHW) + (size_t)t * NHW + hw];
            zf[px][t] = zv;
            zd[px][t] = (double)zv;
        }
        __syncthreads();
        if (t < 8) zs_sh[t] = np_pair128_sq(zf[t]) + np_pair128_sq(zf[t] + 128);
        __syncthreads();

        float zs_reg[8];
        #pragma unroll
        for (int px = 0; px < 8; ++px) zs_reg[px] = zs_sh[px];

        float bvr[8];
        int   bir[8];
        #pragma unroll
        for (int px = 0; px < 8; ++px) { bvr[px] = 3.4e38f; bir[px] = 0; }

        #pragma unroll
        for (int jo = 0; jo < 2; ++jo) {
            const int j0 = t + jo * 512;
            const int j1 = j0 + 256;
            const float* wr0 = w + (size_t)j0 * NC;
            const float* wr1 = w + (size_t)j1 * NC;
            double acc0[8], acc1[8];
            #pragma unroll
            for (int px = 0; px < 8; ++px) { acc0[px] = 0.0; acc1[px] = 0.0; }
            for (int k = 0; k < NC; k += 4) {
                float4 wa = *(const float4*)&wr0[k];
                float4 wb = *(const float4*)&wr1[k];
                const float* wap = (const float*)&wa;
                const float* wbp = (const float*)&wb;
                #pragma unroll
                for (int e = 0; e < 4; ++e) {
                    double wea = (double)wap[e];
                    double web = (double)wbp[e];
                    #pragma unroll
                    for (int px = 0; px < 8; ++px) {
                        double zv = zd[px][k + e];
                        acc0[px] += wea * zv;
                        acc1[px] += web * zv;
                    }
                }
            }
            float ws0 = wsum[j0], ws1 = wsum[j1];
            #pragma unroll
            for (int px = 0; px < 8; ++px) {
                float m0 = (float)acc0[px];
                float s10 = zs_reg[px] + ws0;
                float d0 = s10 - 2.0f * m0;
                if (d0 < bvr[px] || (d0 == bvr[px] && j0 < bir[px])) { bvr[px] = d0; bir[px] = j0; }
                float m1 = (float)acc1[px];
                float s11 = zs_reg[px] + ws1;
                float d1 = s11 - 2.0f * m1;
                if (d1 < bvr[px] || (d1 == bvr[px] && j1 < bir[px])) { bvr[px] = d1; bir[px] = j1; }
            }
        }
        __syncthreads();
        #pragma unroll
        for (int px = 0; px < 8; ++px) {
            rbv[px * 256 + t] = bvr[px];
            rbi[px * 256 + t] = bir[px];
        }
        __syncthreads();
        {
            int px = t >> 5, s = t & 31;
            float bv = rbv[px * 256 + s * 8];
            int   bi = rbi[px * 256 + s * 8];
            #pragma unroll
            for (int e = 1; e < 8; ++e) {
                float v2 = rbv[px * 256 + s * 8 + e];
                int   i2 = rbi[px * 256 + s * 8 + e];
                if (v2 < bv || (v2 == bv && i2 < bi)) { bv = v2; bi = i2; }
            }
            r2v[px][s] = bv;
            r2i[px][s] = bi;
        }
        __syncthreads();
        if (t < 8) {
            float bv = r2v[t][0];
            int   bi = r2i[t][0];
            for (int s = 1; s < 32; ++s) {
                float v2 = r2v[t][s];
                int   i2 = r2i[t][s];
                if (v2 < bv || (v2 == bv && i2 < bi)) { bv = v2; bi = i2; }
            }
            if (g * 8 + t < count) idxf[pix_sh[t]] = (float)bi;
        }
        __syncthreads();
    }
}

// ---- K2a: counts histogram -> ncs ------------------------------------------
__global__ __launch_bounds__(1024) void hist_kernel(const float* __restrict__ idxf,
                                                    float* __restrict__ ncs) {
    __shared__ int h[NE];
    int t = threadIdx.x;
    h[t] = 0;
    __syncthreads();
    int gid = blockIdx.x * 1024 + t;
    #pragma unroll
    for (int i = 0; i < 4; ++i) atomicAdd(&h[(int)idxf[gid + i * 16384]], 1);
    __syncthreads();
    if (h[t]) atomicAdd(&ncs[t], (float)h[t]);
}

// ---- K2b: FUSED z_q out + loss + dw accumulate; one channel per block ------
// Replaces out_kernel + dwsum_kernel: z read once, w gather via LDS column.
__global__ __launch_bounds__(1024) void outdw_kernel(const float* __restrict__ z,
                                                     const float* __restrict__ w,
                                                     const float* __restrict__ idxf,
                                                     const float* __restrict__ ea,
                                                     float* __restrict__ outq,
                                                     float* __restrict__ nea,
                                                     float* __restrict__ lpart) {
    __shared__ float acc[NE];
    __shared__ float wcol[NE];
    __shared__ float ls[16];
    const int c = blockIdx.x;                 // grid 256
    const int t = threadIdx.x;
    acc[t] = 0.0f;
    wcol[t] = w[(size_t)t * NC + c];
    __syncthreads();
    const float* zc = z + (size_t)c * NHW;    // + b*(NC*NHW) + hw
    float* oc = outq + (size_t)c * NHW;
    float lsum = 0.0f;
    #pragma unroll 4
    for (int i = 0; i < 16; ++i) {
        int p0 = i * 4096 + t * 4;            // 4 consecutive pixels, b == i
        size_t a = (size_t)i * (NC * NHW) + (p0 & (NHW - 1));
        float4 zv = *(const float4*)&zc[a];
        float4 iv = *(const float4*)&idxf[p0];
        int id0 = (int)iv.x, id1 = (int)iv.y, id2 = (int)iv.z, id3 = (int)iv.w;
        float4 ov;
        ov.x = wcol[id0]; ov.y = wcol[id1]; ov.z = wcol[id2]; ov.w = wcol[id3];
        *(float4*)&oc[a] = ov;
        float d0 = ov.x - zv.x, d1 = ov.y - zv.y, d2 = ov.z - zv.z, d3 = ov.w - zv.w;
        lsum += d0 * d0 + d1 * d1 + d2 * d2 + d3 * d3;
        atomicAdd(&acc[id0], zv.x);
        atomicAdd(&acc[id1], zv.y);
        atomicAdd(&acc[id2], zv.z);
        atomicAdd(&acc[id3], zv.w);
    }
    #pragma unroll
    for (int off = 32; off > 0; off >>= 1) lsum += __shfl_down(lsum, off);
    if ((t & 63) == 0) ls[t >> 6] = lsum;
    __syncthreads();                          // orders LDS atomics too
    if (t == 0) {
        float s = 0.0f;
        #pragma unroll
        for (int q = 0; q < 16; ++q) s += ls[q];
        lpart[c] = s;
    }
    size_t o = (size_t)t * NC + c;            // code t, channel c
    nea[o] = DECAY * ea[o] + (1.0f - DECAY) * acc[t];
}

// ---- K3: finalize (256 loss partials) --------------------------------------
__global__ __launch_bounds__(1024) void finalize_kernel(const float* __restrict__ cs,
                                                        const float* __restrict__ lpart,
                                                        float* __restrict__ ncs,
                                                        float* __restrict__ cssm,
                                                        float* __restrict__ loss) {
    int t = threadIdx.x;
    float cnt = ncs[t];
    float v = cs[t] * DECAY + (1.0f - DECAY) * cnt;
    ncs[t] = v;
    __shared__ float red[1024];
    red[t] = v;
    __syncthreads();
    for (int s = 512; s > 0; s >>= 1) {
        if (t < s) red[t] += red[t + s];
        __syncthreads();
    }
    float n = red[0];
    __syncthreads();
    cssm[t] = (v + EPS_) / (n + (float)NE * EPS_) * n;
    red[t] = (t < 256) ? lpart[t] : 0.0f;
    __syncthreads();
    for (int s = 512; s > 0; s >>= 1) {
        if (t < s) red[t] += red[t + s];
        __syncthreads();
    }
    if (t == 0) loss[0] = BETA * red[0] / 16777216.0f;
}

// ---- K4: new_weight --------------------------------------------------------
__global__ __launch_bounds__(256) void newweight_kernel(const float* __restrict__ nea,
                                                        const float* __restrict__ cssm,
                                                        float* __restrict__ nw) {
    int lin = blockIdx.x * 256 + threadIdx.x;
    nw[lin] = nea[lin] / cssm[lin >> 8];
}

extern "C" void kernel_launch(void* const* d_in, const int* in_sizes, int n_in,
                              void* d_out, int out_size, void* d_ws, size_t ws_size,
                              hipStream_t stream) {
    const float* z  = (const float*)d_in[0];
    const float* w  = (const float*)d_in[1];
    const float* cs = (const float*)d_in[2];
    const float* ea = (const float*)d_in[3];

    float* out  = (float*)d_out;
    float* loss = out + OFF_LOSS;
    float* idxf = out + OFF_IDXF;
    float* ncs  = out + OFF_NCS;
    float* nea  = out + OFF_NEA;
    float* nw   = out + OFF_NW;

    float* wsf = (float*)d_ws;
    float* wsum = wsf + WS_WSUM;
    float* cssm = wsf + WS_CSSM;
    float* lpart = wsf + WS_LPART;
    int* cnt = (int*)(wsf + WS_CNT);
    unsigned long long* flags = (unsigned long long*)(wsf + WS_FLAGS);
    ushort_t* list = (ushort_t*)(wsf + WS_LIST);

    hipLaunchKernelGGL(init_kernel, dim3(4), dim3(256), 0, stream, ncs, cnt);
    hipLaunchKernelGGL(wsum_kernel, dim3(16), dim3(64), 0, stream, w, wsum);

    if (ws_size >= (size_t)WS_END * 4) {
        _Float16* wf16 = (_Float16*)(wsf + WS_WF16);
        _Float16* zf16 = (_Float16*)(wsf + WS_ZF16);
        hipLaunchKernelGGL(wpack_kernel, dim3(1024), dim3(256), 0, stream, w, wf16);
        hipLaunchKernelGGL(zpack_kernel, dim3(1024, 4), dim3(256), 0, stream, z, zf16);
        hipLaunchKernelGGL(gemm2_kernel, dim3(512), dim3(256), 0, stream,
                           wf16, zf16, wsum, idxf, list, cnt);
    } else {
        hipLaunchKernelGGL(argmin_kernel, dim3(1024), dim3(256), 0, stream, z, w, wsum, idxf, flags);
        hipLaunchKernelGGL(gather_kernel, dim3(256), dim3(256), 0, stream, flags, list, cnt);
    }

    hipLaunchKernelGGL(fixup3_kernel, dim3(256), dim3(256), 0, stream, z, w, wsum, list, cnt, idxf);
    hipLaunchKernelGGL(hist_kernel, dim3(16), dim3(1024), 0, stream, idxf, ncs);
    hipLaunchKernelGGL(outdw_kernel, dim3(256), dim3(1024), 0, stream, z, w, idxf, ea, out, nea, lpart);
    hipLaunchKernelGGL(finalize_kernel, dim3(1), dim3(1024), 0, stream, cs, lpart, ncs, cssm, loss);
    hipLaunchKernelGGL(newweight_kernel, dim3(1024), dim3(256), 0, stream, nea, cssm, nw);
}

// Round 13
// 299.038 us; speedup vs baseline: 8.1732x; 1.0005x over previous
//
#include <hip/hip_runtime.h>
#include <hip/hip_bf16.h>

typedef unsigned short ushort_t;
typedef __attribute__((ext_vector_type(8))) _Float16 half8;
typedef __attribute__((ext_vector_type(4))) float f32x4;

// Problem constants
#define NB    16
#define NC    256
#define NHW   4096
#define NPIX  65536
#define NE    1024
#define BETA  0.25f
#define DECAY 0.99f
#define EPS_  1e-5f
#define GAP_FLAG 1.25e-4f

// d_out layout (floats)
#define OFF_LOSS 16777216
#define OFF_IDXF 16777217
#define OFF_NCS  16842753
#define OFF_NEA  16843777
#define OFF_NW   17105921

// ws layout (float offsets)
#define WS_WSUM  0
#define WS_CSSM  1024
#define WS_LPART 2048
#define WS_CNT   3072
#define WS_FLAGS 3104
#define WS_LIST  5152
#define WS_WF16  40960                    // 1024*256 fp16 = 131072 float units
#define WS_ZF16  (WS_WF16 + 131072)       // 65536*256 fp16 = 8388608 float units
#define WS_IDXI  (WS_ZF16 + 8388608)      // 65536 int (aligned idx copy)
#define WS_END   (WS_IDXI + 65536)

__device__ __forceinline__ float sq_nofma(float x) {
    float s = x * x;
    asm volatile("" : "+v"(s));
    return s;
}

__device__ __forceinline__ float np_pair128_sq(const float* __restrict__ a) {
    float r[8];
    #pragma unroll
    for (int m = 0; m < 8; ++m) r[m] = sq_nofma(a[m]);
    for (int i = 8; i < 128; i += 8) {
        #pragma unroll
        for (int m = 0; m < 8; ++m) r[m] += sq_nofma(a[i + m]);
    }
    return ((r[0] + r[1]) + (r[2] + r[3])) + ((r[4] + r[5]) + (r[6] + r[7]));
}

__device__ __forceinline__ void gload16(const void* g, void* ldsp) {
    __builtin_amdgcn_global_load_lds((const __attribute__((address_space(1))) unsigned int*)g,
                                     (__attribute__((address_space(3))) unsigned int*)ldsp,
                                     16, 0, 0);
}

// ---- K0a: zero counts accumulator + list counter ---------------------------
__global__ __launch_bounds__(256) void init_kernel(float* __restrict__ ncs,
                                                   int* __restrict__ cnt) {
    int gid = blockIdx.x * 256 + threadIdx.x;
    if (gid < NE) ncs[gid] = 0.0f;
    if (gid == 0) cnt[0] = 0;
}

// ---- K0b: wsum[j] = np.float32 pairwise sum of w[j][:]^2 -------------------
__global__ __launch_bounds__(64) void wsum_kernel(const float* __restrict__ w,
                                                  float* __restrict__ wsum) {
    int j = blockIdx.x * 64 + threadIdx.x;
    const float* wr = w + (size_t)j * NC;
    wsum[j] = np_pair128_sq(wr) + np_pair128_sq(wr + 128);
}

// ---- P1: pack w -> fp16, scaled by 1024 ------------------------------------
__global__ __launch_bounds__(256) void wpack_kernel(const float* __restrict__ w,
                                                    _Float16* __restrict__ wf) {
    int i = blockIdx.x * 256 + threadIdx.x;
    wf[i] = (_Float16)(w[i] * 1024.0f);
}

// ---- P2: pack z -> fp16 [65536 pix][256 k] (LDS transpose) -----------------
__global__ __launch_bounds__(256) void zpack_kernel(const float* __restrict__ z,
                                                    _Float16* __restrict__ zf) {
    __shared__ float zs[64 * 65];
    const int t = threadIdx.x;
    const int P0 = blockIdx.x * 64;
    const int b = P0 >> 12, hw0 = P0 & (NHW - 1);
    const int K0 = blockIdx.y * 64;
    const int hw = t & 63, cq = t >> 6;
    const float* zb = z + (size_t)b * (NC * NHW) + hw0 + hw;
    #pragma unroll
    for (int i = 0; i < 16; ++i) {
        int kl = cq * 16 + i;
        zs[hw * 65 + kl] = zb[(size_t)(K0 + kl) * NHW];
    }
    __syncthreads();
    const int p = t >> 2, kq = t & 3;
    size_t obase = (size_t)(P0 + p) * NC + K0 + kq * 16;
    #pragma unroll
    for (int h2 = 0; h2 < 2; ++h2) {
        half8 v;
        #pragma unroll
        for (int j2 = 0; j2 < 8; ++j2)
            v[j2] = (_Float16)zs[p * 65 + kq * 16 + h2 * 8 + j2];
        *(half8*)&zf[obase + h2 * 8] = v;
    }
}

// ---- K1: fp16 MFMA distance GEMM, code-tile loop inside, persistent z ------
__global__ __launch_bounds__(256) void gemm2_kernel(const _Float16* __restrict__ wf,
                                                    const _Float16* __restrict__ zf,
                                                    const float* __restrict__ wsum,
                                                    float* __restrict__ idxf,
                                                    int* __restrict__ idxi,
                                                    ushort_t* __restrict__ list,
                                                    int* __restrict__ cnt) {
    __shared__ __align__(16) _Float16 zt[128 * 256];   // 64 KB
    __shared__ __align__(16) _Float16 wt[128 * 32];    // 8 KB
    __shared__ float bvx[256], svx[256];
    __shared__ int   bix[256];
    __shared__ float rbv[128], rsv[128];
    __shared__ int   rbi[128];

    const int t = threadIdx.x;
    const int l = t & 63;
    const int w = t >> 6;
    const int P0 = blockIdx.x * 128;
    const int wc = w >> 1, wp = w & 1;

    // persistent z stage: LDS(row,chunk) = global(row, chunk ^ (row&7))
    #pragma unroll
    for (int i = 0; i < 16; ++i) {
        int row = w * 32 + i * 2 + (l >> 5);
        int gc = (l & 31) ^ (row & 7);
        gload16(zf + (size_t)(P0 + row) * NC + gc * 8,
                &zt[w * 8192 + i * 512 + l * 8]);
    }
    if (t < 128) { rbv[t] = 3.4e38f; rsv[t] = 3.4e38f; rbi[t] = 0; }
    __syncthreads();

    for (int ct = 0; ct < 8; ++ct) {
        f32x4 acc[4][4];
        #pragma unroll
        for (int m = 0; m < 4; ++m)
            #pragma unroll
            for (int n = 0; n < 4; ++n)
                #pragma unroll
                for (int e = 0; e < 4; ++e) acc[m][n][e] = 0.0f;

        for (int ks = 0; ks < 8; ++ks) {
            if (ks) __syncthreads();
            #pragma unroll
            for (int i = 0; i < 2; ++i) {
                int row = w * 32 + i * 16 + (l >> 2);
                int gc = (l & 3) ^ ((l >> 3) & 3);
                gload16(wf + (size_t)(ct * 128 + row) * NC + ks * 32 + gc * 8,
                        &wt[w * 1024 + i * 512 + l * 8]);
            }
            __syncthreads();

            half8 a[4], b[4];
            #pragma unroll
            for (int m = 0; m < 4; ++m) {
                int row = wc * 64 + m * 16 + (l & 15);
                int g = (l >> 4) ^ ((row >> 1) & 3);
                a[m] = *(const half8*)&wt[row * 32 + g * 8];
            }
            #pragma unroll
            for (int n = 0; n < 4; ++n) {
                int row = wp * 64 + n * 16 + (l & 15);
                int chunk = (ks * 4 + (l >> 4)) ^ (row & 7);
                b[n] = *(const half8*)&zt[row * 256 + chunk * 8];
            }
            #pragma unroll
            for (int m = 0; m < 4; ++m)
                #pragma unroll
                for (int n = 0; n < 4; ++n)
                    acc[m][n] = __builtin_amdgcn_mfma_f32_16x16x32_f16(a[m], b[n], acc[m][n], 0, 0, 0);
        }

        float en[4][4];
        #pragma unroll
        for (int m = 0; m < 4; ++m)
            #pragma unroll
            for (int r = 0; r < 4; ++r)
                en[m][r] = wsum[ct * 128 + wc * 64 + m * 16 + (l >> 4) * 4 + r];

        #pragma unroll
        for (int n = 0; n < 4; ++n) {
            float bv = 3.4e38f, sv = 3.4e38f;
            int bi = 0;
            #pragma unroll
            for (int m = 0; m < 4; ++m)
                #pragma unroll
                for (int r = 0; r < 4; ++r) {
                    float s = en[m][r] - acc[m][n][r] * 0.001953125f;  // 2^-9
                    int code = ct * 128 + wc * 64 + m * 16 + (l >> 4) * 4 + r;
                    if (s < bv) { sv = bv; bv = s; bi = code; }
                    else if (s < sv) sv = s;
                }
            #pragma unroll
            for (int x = 16; x <= 32; x <<= 1) {
                float v2 = __shfl_xor(bv, x);
                float s2 = __shfl_xor(sv, x);
                int   i2 = __shfl_xor(bi, x);
                if (v2 < bv || (v2 == bv && i2 < bi)) { sv = fminf(bv, s2); bv = v2; bi = i2; }
                else sv = fminf(sv, v2);
            }
            if ((l >> 4) == 0) {
                int lp = wp * 64 + n * 16 + l;
                bvx[wc * 128 + lp] = bv;
                svx[wc * 128 + lp] = sv;
                bix[wc * 128 + lp] = bi;
            }
        }
        __syncthreads();
        if (t < 128) {
            float bv = bvx[t], sv = svx[t];
            int bi = bix[t];
            float v2 = bvx[128 + t], s2 = svx[128 + t];
            int i2 = bix[128 + t];
            if (v2 < bv || (v2 == bv && i2 < bi)) { sv = fminf(bv, s2); bv = v2; bi = i2; }
            else sv = fminf(sv, v2);
            if (bv < rbv[t]) { rsv[t] = fminf(rbv[t], sv); rbv[t] = bv; rbi[t] = bi; }
            else rsv[t] = fminf(rsv[t], bv);
        }
        __syncthreads();
    }

    if (t < 128) {
        int pix = P0 + t;
        idxf[pix] = (float)rbi[t];
        idxi[pix] = rbi[t];
        if (rsv[t] - rbv[t] < GAP_FLAG) {
            int pos = atomicAdd(cnt, 1);
            list[pos] = (ushort_t)pix;
        }
    }
}

// ================== FALLBACK PATH (round-7 argmin), used if ws too small ====
__global__ __launch_bounds__(256) void argmin_kernel(const float* __restrict__ z,
                                                     const float* __restrict__ w,
                                                     const float* __restrict__ enorm,
                                                     float* __restrict__ idxf,
                                                     int* __restrict__ idxi,
                                                     unsigned long long* __restrict__ flags) {
    __shared__ __align__(16) float smem[64 * 68 + 128 * 68];
    float* zt = smem;
    float* wt = smem + 64 * 68;
    const int t = threadIdx.x;
    const int pr = t & 7;
    const int cr = t >> 3;
    const int P0 = blockIdx.x * 64;
    const int b = P0 >> 12;
    const int hw0 = P0 & (NHW - 1);
    const float* zb = z + (size_t)b * (NC * NHW) + hw0;
    float bestv[8], secv[8];
    int besti[8];
    #pragma unroll
    for (int i = 0; i < 8; ++i) { bestv[i] = 3.4e38f; secv[i] = 3.4e38f; besti[i] = 0; }
    for (int cc = 0; cc < 8; ++cc) {
        float acc[8][4];
        #pragma unroll
        for (int i = 0; i < 8; ++i)
            #pragma unroll
            for (int j = 0; j < 4; ++j) acc[i][j] = 0.0f;
        for (int kc = 0; kc < 4; ++kc) {
            {
                int p = t & 63;
                int k0 = (t >> 6) * 16;
                int f2 = ((p >> 3) & 3) << 2;
                #pragma unroll
                for (int i = 0; i < 16; ++i) {
                    int k = k0 + i;
                    zt[p * 68 + (k ^ f2)] = zb[(size_t)(kc * 64 + k) * NHW + p];
                }
            }
            {
                #pragma unroll
                for (int i = 0; i < 8; ++i) {
                    int f = t + 256 * i;
                    int jj = f >> 4;
                    int k4 = f & 15;
                    float4 v = *(const float4*)&w[(size_t)(cc * 128 + jj) * NC + kc * 64 + k4 * 4];
                    *(float4*)&wt[jj * 68 + k4 * 4] = v;
                }
            }
            __syncthreads();
            #pragma unroll 2
            for (int k = 0; k < 64; k += 4) {
                float4 za[8], wb[4];
                #pragma unroll
                for (int i = 0; i < 8; ++i)
                    za[i] = *(float4*)&zt[(pr + 8 * i) * 68 + (k ^ ((i & 3) << 2))];
                #pragma unroll
                for (int j = 0; j < 4; ++j)
                    wb[j] = *(float4*)&wt[(cr + 32 * j) * 68 + k];
                #pragma unroll
                for (int i = 0; i < 8; ++i)
                    #pragma unroll
                    for (int j = 0; j < 4; ++j)
                        acc[i][j] += za[i].x * wb[j].x + za[i].y * wb[j].y +
                                     za[i].z * wb[j].z + za[i].w * wb[j].w;
            }
            __syncthreads();
        }
        #pragma unroll
        for (int j = 0; j < 4; ++j) {
            int code = cc * 128 + cr + 32 * j;
            float enj = enorm[code];
            #pragma unroll
            for (int i = 0; i < 8; ++i) {
                float s = enj - 2.0f * acc[i][j];
                if (s < bestv[i]) { secv[i] = bestv[i]; bestv[i] = s; besti[i] = code; }
                else if (s < secv[i]) secv[i] = s;
            }
        }
    }
    float* rv = smem;
    int* ri = (int*)(smem + 2048);
    float* rs = smem + 4096;
    #pragma unroll
    for (int i = 0; i < 8; ++i) {
        int p = pr + 8 * i;
        rv[p * 32 + cr] = bestv[i];
        ri[p * 32 + cr] = besti[i];
        rs[p * 32 + cr] = secv[i];
    }
    __syncthreads();
    if (t < 64) {
        int p = t;
        float bv = rv[p * 32], sv = rs[p * 32];
        int bi = ri[p * 32];
        for (int s2 = 1; s2 < 32; ++s2) {
            float v = rv[p * 32 + s2];
            float v2 = rs[p * 32 + s2];
            int ii = ri[p * 32 + s2];
            if (v < bv) { sv = bv; bv = v; bi = ii; }
            else {
                if (v < sv) sv = v;
                if (v == bv && ii < bi) bi = ii;
            }
            if (v2 < sv) sv = v2;
        }
        idxf[P0 + p] = (float)bi;
        idxi[P0 + p] = bi;
        unsigned long long mask = __ballot((sv - bv) < GAP_FLAG);
        if (t == 0) flags[blockIdx.x] = mask;
    }
}

__global__ __launch_bounds__(256) void gather_kernel(const unsigned long long* __restrict__ flags,
                                                     ushort_t* __restrict__ list,
                                                     int* __restrict__ cnt) {
    int p = blockIdx.x * 256 + threadIdx.x;
    unsigned long long m = flags[p >> 6];
    if ((m >> (p & 63)) & 1ULL) {
        int pos = atomicAdd(cnt, 1);
        list[pos] = (ushort_t)p;
    }
}
// ================== end fallback ============================================

// ---- K1b: np-fp32-mimic re-argmin, 8 flagged pixels per block --------------
__global__ __launch_bounds__(256) void fixup3_kernel(const float* __restrict__ z,
                                                     const float* __restrict__ w,
                                                     const float* __restrict__ wsum,
                                                     const ushort_t* __restrict__ list,
                                                     const int* __restrict__ cnt,
                                                     float* __restrict__ idxf,
                                                     int* __restrict__ idxi) {
    const int count = cnt[0];
    if (count == 0) return;
    const int ngroups = (count + 7) >> 3;
    const int t = threadIdx.x;

    __shared__ __align__(16) char smem_raw[16384 + 8192];
    double (*zd)[NC] = (double(*)[NC])smem_raw;
    float  (*zf)[NC] = (float(*)[NC])(smem_raw + 16384);
    float* rbv = (float*)(smem_raw + 16384);
    int*   rbi = (int*)smem_raw;
    __shared__ float zs_sh[8];
    __shared__ int   pix_sh[8];
    __shared__ float r2v[8][32];
    __shared__ int   r2i[8][32];

    for (int g = blockIdx.x; g < ngroups; g += gridDim.x) {
        if (t < 8) {
            int i = g * 8 + t;
            pix_sh[t] = (i < count) ? (int)list[i] : (int)list[0];
        }
        __syncthreads();
        #pragma unroll
        for (int px = 0; px < 8; ++px) {
            int p = pix_sh[px];
            int b = p >> 12, hw = p & (NHW - 1);
            float zv = z[(size_t)b * (NC * NHW) + (size_t)t * NHW + hw];
            zf[px][t] = zv;
            zd[px][t] = (double)zv;
        }
        __syncthreads();
        if (t < 8) zs_sh[t] = np_pair128_sq(zf[t]) + np_pair128_sq(zf[t] + 128);
        __syncthreads();

        float zs_reg[8];
        #pragma unroll
        for (int px = 0; px < 8; ++px) zs_reg[px] = zs_sh[px];

        float bvr[8];
        int   bir[8];
        #pragma unroll
        for (int px = 0; px < 8; ++px) { bvr[px] = 3.4e38f; bir[px] = 0; }

        #pragma unroll
        for (int jo = 0; jo < 2; ++jo) {
            const int j0 = t + jo * 512;
            const int j1 = j0 + 256;
            const float* wr0 = w + (size_t)j0 * NC;
            const float* wr1 = w + (size_t)j1 * NC;
            double acc0[8], acc1[8];
            #pragma unroll
            for (int px = 0; px < 8; ++px) { acc0[px] = 0.0; acc1[px] = 0.0; }
            for (int k = 0; k < NC; k += 4) {
                float4 wa = *(const float4*)&wr0[k];
                float4 wb = *(const float4*)&wr1[k];
                const float* wap = (const float*)&wa;
                const float* wbp = (const float*)&wb;
                #pragma unroll
                for (int e = 0; e < 4; ++e) {
                    double wea = (double)wap[e];
                    double web = (double)wbp[e];
                    #pragma unroll
                    for (int px = 0; px < 8; ++px) {
                        double zv = zd[px][k + e];
                        acc0[px] += wea * zv;
                        acc1[px] += web * zv;
                    }
                }
            }
            float ws0 = wsum[j0], ws1 = wsum[j1];
            #pragma unroll
            for (int px = 0; px < 8; ++px) {
                float m0 = (float)acc0[px];
                float s10 = zs_reg[px] + ws0;
                float d0 = s10 - 2.0f * m0;
                if (d0 < bvr[px] || (d0 == bvr[px] && j0 < bir[px])) { bvr[px] = d0; bir[px] = j0; }
                float m1 = (float)acc1[px];
                float s11 = zs_reg[px] + ws1;
                float d1 = s11 - 2.0f * m1;
                if (d1 < bvr[px] || (d1 == bvr[px] && j1 < bir[px])) { bvr[px] = d1; bir[px] = j1; }
            }
        }
        __syncthreads();
        #pragma unroll
        for (int px = 0; px < 8; ++px) {
            rbv[px * 256 + t] = bvr[px];
            rbi[px * 256 + t] = bir[px];
        }
        __syncthreads();
        {
            int px = t >> 5, s = t & 31;
            float bv = rbv[px * 256 + s * 8];
            int   bi = rbi[px * 256 + s * 8];
            #pragma unroll
            for (int e = 1; e < 8; ++e) {
                float v2 = rbv[px * 256 + s * 8 + e];
                int   i2 = rbi[px * 256 + s * 8 + e];
                if (v2 < bv || (v2 == bv && i2 < bi)) { bv = v2; bi = i2; }
            }
            r2v[px][s] = bv;
            r2i[px][s] = bi;
        }
        __syncthreads();
        if (t < 8) {
            float bv = r2v[t][0];
            int   bi = r2i[t][0];
            for (int s = 1; s < 32; ++s) {
                float v2 = r2v[t][s];
                int   i2 = r2i[t][s];
                if (v2 < bv || (v2 == bv && i2 < bi)) { bv = v2; bi = i2; }
            }
            if (g * 8 + t < count) {
                idxf[pix_sh[t]] = (float)bi;
                idxi[pix_sh[t]] = bi;
            }
        }
        __syncthreads();
    }
}

// ---- K2a: counts histogram -> ncs ------------------------------------------
__global__ __launch_bounds__(1024) void hist_kernel(const int* __restrict__ idxi,
                                                    float* __restrict__ ncs) {
    __shared__ int h[NE];
    int t = threadIdx.x;
    h[t] = 0;
    __syncthreads();
    int gid = blockIdx.x * 1024 + t;
    #pragma unroll
    for (int i = 0; i < 4; ++i) atomicAdd(&h[idxi[gid + i * 16384]], 1);
    __syncthreads();
    if (h[t]) atomicAdd(&ncs[t], (float)h[t]);
}

// ---- K2b: FUSED z_q out + loss + dw partial; (channel, b-half) per block ---
// Partial code-sums written (transposed) into dwp = nea/nw regions (scratch).
__global__ __launch_bounds__(1024) void outdw_kernel(const float* __restrict__ z,
                                                     const float* __restrict__ w,
                                                     const int* __restrict__ idxi,
                                                     float* __restrict__ outq,
                                                     float* __restrict__ dw0,
                                                     float* __restrict__ dw1,
                                                     float* __restrict__ lpart) {
    __shared__ float acc[NE];
    __shared__ float wcol[NE];
    __shared__ float ls[16];
    const int c = blockIdx.x;                 // 256 channels
    const int part = blockIdx.y;              // 2 b-halves
    const int t = threadIdx.x;
    acc[t] = 0.0f;
    wcol[t] = w[(size_t)t * NC + c];
    __syncthreads();
    const float* zc = z + (size_t)c * NHW;
    float* oc = outq + (size_t)c * NHW;
    float lsum = 0.0f;
    #pragma unroll
    for (int i = 0; i < 8; ++i) {
        int b = part * 8 + i;
        int p0 = b * 4096 + t * 4;            // 4 consecutive pixels in batch b
        size_t a = (size_t)b * (NC * NHW) + t * 4;
        float4 zv = *(const float4*)&zc[a];
        int4 iv = *(const int4*)&idxi[p0];
        float4 ov;
        ov.x = wcol[iv.x]; ov.y = wcol[iv.y]; ov.z = wcol[iv.z]; ov.w = wcol[iv.w];
        *(float4*)&oc[a] = ov;
        float d0 = ov.x - zv.x, d1 = ov.y - zv.y, d2 = ov.z - zv.z, d3 = ov.w - zv.w;
        lsum += d0 * d0 + d1 * d1 + d2 * d2 + d3 * d3;
        atomicAdd(&acc[iv.x], zv.x);
        atomicAdd(&acc[iv.y], zv.y);
        atomicAdd(&acc[iv.z], zv.z);
        atomicAdd(&acc[iv.w], zv.w);
    }
    #pragma unroll
    for (int off = 32; off > 0; off >>= 1) lsum += __shfl_down(lsum, off);
    if ((t & 63) == 0) ls[t >> 6] = lsum;
    __syncthreads();                          // orders LDS atomics too
    if (t == 0) {
        float s = 0.0f;
        #pragma unroll
        for (int q = 0; q < 16; ++q) s += ls[q];
        lpart[c * 2 + part] = s;
    }
    float* dwp = part ? dw1 : dw0;
    dwp[(size_t)t * NC + c] = acc[t];         // raw partial sum, code t, chan c
}

// ---- K3: finalize (512 loss partials) --------------------------------------
__global__ __launch_bounds__(1024) void finalize_kernel(const float* __restrict__ cs,
                                                        const float* __restrict__ lpart,
                                                        float* __restrict__ ncs,
                                                        float* __restrict__ cssm,
                                                        float* __restrict__ loss) {
    int t = threadIdx.x;
    float cnt = ncs[t];
    float v = cs[t] * DECAY + (1.0f - DECAY) * cnt;
    ncs[t] = v;
    __shared__ float red[1024];
    red[t] = v;
    __syncthreads();
    for (int s = 512; s > 0; s >>= 1) {
        if (t < s) red[t] += red[t + s];
        __syncthreads();
    }
    float n = red[0];
    __syncthreads();
    cssm[t] = (v + EPS_) / (n + (float)NE * EPS_) * n;
    red[t] = (t < 512) ? lpart[t] : 0.0f;
    __syncthreads();
    for (int s = 512; s > 0; s >>= 1) {
        if (t < s) red[t] += red[t + s];
        __syncthreads();
    }
    if (t == 0) loss[0] = BETA * red[0] / 16777216.0f;
}

// ---- K4: nea + new_weight in-place (nea/nw currently hold dw partials) -----
__global__ __launch_bounds__(256) void neaw_kernel(const float* __restrict__ ea,
                                                   const float* __restrict__ cssm,
                                                   float* __restrict__ nea,
                                                   float* __restrict__ nw) {
    int lin = blockIdx.x * 256 + threadIdx.x;
    float dw = nea[lin] + nw[lin];            // two partials (same addr this thread)
    float v = DECAY * ea[lin] + (1.0f - DECAY) * dw;
    nea[lin] = v;
    nw[lin] = v / cssm[lin >> 8];
}

extern "C" void kernel_launch(void* const* d_in, const int* in_sizes, int n_in,
                              void* d_out, int out_size, void* d_ws, size_t ws_size,
                              hipStream_t stream) {
    const float* z  = (const float*)d_in[0];
    const float* w  = (const float*)d_in[1];
    const float* cs = (const float*)d_in[2];
    const float* ea = (const float*)d_in[3];

    float* out  = (float*)d_out;
    float* loss = out + OFF_LOSS;
    float* idxf = out + OFF_IDXF;
    float* ncs  = out + OFF_NCS;
    float* nea  = out + OFF_NEA;
    float* nw   = out + OFF_NW;

    float* wsf = (float*)d_ws;
    float* wsum = wsf + WS_WSUM;
    float* cssm = wsf + WS_CSSM;
    float* lpart = wsf + WS_LPART;
    int* cnt = (int*)(wsf + WS_CNT);
    unsigned long long* flags = (unsigned long long*)(wsf + WS_FLAGS);
    ushort_t* list = (ushort_t*)(wsf + WS_LIST);
    int* idxi = (int*)(wsf + WS_IDXI);

    hipLaunchKernelGGL(init_kernel, dim3(4), dim3(256), 0, stream, ncs, cnt);
    hipLaunchKernelGGL(wsum_kernel, dim3(16), dim3(64), 0, stream, w, wsum);

    if (ws_size >= (size_t)WS_END * 4) {
        _Float16* wf16 = (_Float16*)(wsf + WS_WF16);
        _Float16* zf16 = (_Float16*)(wsf + WS_ZF16);
        hipLaunchKernelGGL(wpack_kernel, dim3(1024), dim3(256), 0, stream, w, wf16);
        hipLaunchKernelGGL(zpack_kernel, dim3(1024, 4), dim3(256), 0, stream, z, zf16);
        hipLaunchKernelGGL(gemm2_kernel, dim3(512), dim3(256), 0, stream,
                           wf16, zf16, wsum, idxf, idxi, list, cnt);
    } else {
        hipLaunchKernelGGL(argmin_kernel, dim3(1024), dim3(256), 0, stream, z, w, wsum, idxf, idxi, flags);
        hipLaunchKernelGGL(gather_kernel, dim3(256), dim3(256), 0, stream, flags, list, cnt);
    }

    hipLaunchKernelGGL(fixup3_kernel, dim3(256), dim3(256), 0, stream, z, w, wsum, list, cnt, idxf, idxi);
    hipLaunchKernelGGL(hist_kernel, dim3(16), dim3(1024), 0, stream, idxi, ncs);
    hipLaunchKernelGGL(outdw_kernel, dim3(256, 2), dim3(1024), 0, stream, z, w, idxi, out, nea, nw, lpart);
    hipLaunchKernelGGL(finalize_kernel, dim3(1), dim3(1024), 0, stream, cs, lpart, ncs, cssm, loss);
    hipLaunchKernelGGL(neaw_kernel, dim3(1024), dim3(256), 0, stream, ea, cssm, nea, nw);
}